// Round 4
// baseline (910.251 us; speedup 1.0000x reference)
//
#include <hip/hip_runtime.h>
#include <math.h>

typedef __bf16 bf16_t;
typedef bf16_t bf16x8 __attribute__((ext_vector_type(8)));
typedef bf16_t bf16x4 __attribute__((ext_vector_type(4)));
typedef float  f32x4  __attribute__((ext_vector_type(4)));

#define T_TOK 8192
#define DM 1024
#define DF 4096
#define NE 8
#define NP 16384  // total token-expert pairs = T_TOK * 2
#define NKT1 (DM / 64)   // 16 K-tiles for GEMM1
#define NKT2 (DF / 64)   // 64 K-tiles for GEMM2

__device__ __forceinline__ f32x4 mfma_bf16(bf16x8 a, bf16x8 b, f32x4 c) {
  return __builtin_amdgcn_mfma_f32_16x16x32_bf16(a, b, c, 0, 0, 0);
}

__device__ __forceinline__ void gload16(const void* g, void* l) {
  __builtin_amdgcn_global_load_lds((const __attribute__((address_space(1))) void*)g,
                                   (__attribute__((address_space(3))) void*)l, 16, 0, 0);
}

// meta layout (ints): [0..7]=cnt1 [8..15]=cnt2 [16..23]=cursor [24..31]=off
// [32..39]=probsum(float) [40]=zsum(float)

// ============================ router ============================
__global__ __launch_bounds__(256) void k_router(
    const float* __restrict__ x, const float* __restrict__ gate_w,
    const float* __restrict__ ln_g, const float* __restrict__ ln_b,
    float* __restrict__ out, bf16_t* __restrict__ xn,
    int* __restrict__ eidx, float* __restrict__ gts, int* __restrict__ meta)
{
  int* cnt1 = meta;
  int* cnt2 = meta + 8;
  float* probsum = (float*)(meta + 32);
  float* zsum    = (float*)(meta + 40);

  __shared__ float sprob[8];
  __shared__ float sz;
  __shared__ int sc1[8], sc2[8];
  if (threadIdx.x < 8) { sprob[threadIdx.x] = 0.f; sc1[threadIdx.x] = 0; sc2[threadIdx.x] = 0; }
  if (threadIdx.x == 8) sz = 0.f;
  __syncthreads();

  int lane = threadIdx.x & 63, wv = threadIdx.x >> 6;
  int t = blockIdx.x * 4 + wv;
  const float* xt = x + (size_t)t * DM;

  float4 v[4];
  float s1 = 0.f, s2 = 0.f;
  #pragma unroll
  for (int c = 0; c < 4; ++c) {
    v[c] = *(const float4*)(xt + c * 256 + lane * 4);
    s1 += v[c].x + v[c].y + v[c].z + v[c].w;
    s2 += v[c].x * v[c].x + v[c].y * v[c].y + v[c].z * v[c].z + v[c].w * v[c].w;
  }
  #pragma unroll
  for (int o = 32; o > 0; o >>= 1) { s1 += __shfl_xor(s1, o, 64); s2 += __shfl_xor(s2, o, 64); }
  float mu = s1 * (1.f / DM);
  float var = s2 * (1.f / DM) - mu * mu;
  float rstd = rsqrtf(var + 1e-5f);

  float xv[16];
  #pragma unroll
  for (int c = 0; c < 4; ++c) {
    int d = c * 256 + lane * 4;
    float4 g4 = *(const float4*)(ln_g + d);
    float4 b4 = *(const float4*)(ln_b + d);
    xv[c*4+0] = (v[c].x - mu) * rstd * g4.x + b4.x;
    xv[c*4+1] = (v[c].y - mu) * rstd * g4.y + b4.y;
    xv[c*4+2] = (v[c].z - mu) * rstd * g4.z + b4.z;
    xv[c*4+3] = (v[c].w - mu) * rstd * g4.w + b4.w;
    *(float4*)(out + (size_t)t * DM + d) = v[c];  // residual init
    bf16x4 pk = { (bf16_t)xv[c*4+0], (bf16_t)xv[c*4+1], (bf16_t)xv[c*4+2], (bf16_t)xv[c*4+3] };
    *(bf16x4*)(xn + (size_t)t * DM + d) = pk;
  }

  float lg[8];
  #pragma unroll
  for (int e = 0; e < 8; ++e) {
    float p = 0.f;
    #pragma unroll
    for (int c = 0; c < 4; ++c) {
      int d = c * 256 + lane * 4;
      float4 g4 = *(const float4*)(gate_w + e * DM + d);
      p += xv[c*4+0] * g4.x + xv[c*4+1] * g4.y + xv[c*4+2] * g4.z + xv[c*4+3] * g4.w;
    }
    #pragma unroll
    for (int o = 32; o > 0; o >>= 1) p += __shfl_xor(p, o, 64);
    lg[e] = p;
  }

  if (lane == 0) {
    float m = -1e30f;
    #pragma unroll
    for (int e = 0; e < 8; ++e) { lg[e] = fminf(fmaxf(lg[e], -10.f), 10.f); m = fmaxf(m, lg[e]); }
    float pr[8]; float se = 0.f;
    #pragma unroll
    for (int e = 0; e < 8; ++e) { pr[e] = expf(lg[e] - m); se += pr[e]; }
    float inv = 1.f / se;
    #pragma unroll
    for (int e = 0; e < 8; ++e) pr[e] *= inv;
    float lse = m + logf(se);

    int e0 = 0; float p0 = pr[0];
    #pragma unroll
    for (int e = 1; e < 8; ++e) if (pr[e] > p0) { p0 = pr[e]; e0 = e; }
    int e1 = -1; float p1 = -1.f;
    #pragma unroll
    for (int e = 0; e < 8; ++e) if (e != e0 && pr[e] > p1) { p1 = pr[e]; e1 = e; }
    float s = p0 + p1 + 1e-8f;
    eidx[t*2]   = e0; eidx[t*2+1] = e1;
    gts[t*2]    = p0 / s; gts[t*2+1] = p1 / s;

    atomicAdd(&sc1[e0], 1);
    atomicAdd(&sc2[e0], 1);
    atomicAdd(&sc2[e1], 1);
    #pragma unroll
    for (int e = 0; e < 8; ++e) atomicAdd(&sprob[e], pr[e]);
    atomicAdd(&sz, lse * lse);
  }
  __syncthreads();
  if (threadIdx.x < 8) {
    if (sc1[threadIdx.x]) atomicAdd(&cnt1[threadIdx.x], sc1[threadIdx.x]);
    if (sc2[threadIdx.x]) atomicAdd(&cnt2[threadIdx.x], sc2[threadIdx.x]);
    atomicAdd(&probsum[threadIdx.x], sprob[threadIdx.x]);
  }
  if (threadIdx.x == 8) atomicAdd(zsum, sz);
}

// ========== weight convert + transpose: src [R][C] fp32 -> dst [C][R] bf16 ==========
__global__ __launch_bounds__(256) void k_convT(
    const float* __restrict__ src, bf16_t* __restrict__ dst, int R, int C)
{
  __shared__ float tile[64][65];
  int e = blockIdx.z;
  const float* s = src + (size_t)e * R * C;
  bf16_t* d = dst + (size_t)e * R * C;
  int c0 = blockIdx.x * 64, r0 = blockIdx.y * 64;
  int t = threadIdx.x;
  #pragma unroll
  for (int i = 0; i < 4; ++i) {
    int idx = i * 256 + t;
    int r = idx >> 4, c4 = (idx & 15) * 4;
    float4 v = *(const float4*)(s + (size_t)(r0 + r) * C + c0 + c4);
    tile[r][c4]   = v.x; tile[r][c4+1] = v.y;
    tile[r][c4+2] = v.z; tile[r][c4+3] = v.w;
  }
  __syncthreads();
  #pragma unroll
  for (int i = 0; i < 4; ++i) {
    int idx = i * 256 + t;
    int c = idx >> 4, r4 = (idx & 15) * 4;
    bf16x4 pk = { (bf16_t)tile[r4][c], (bf16_t)tile[r4+1][c],
                  (bf16_t)tile[r4+2][c], (bf16_t)tile[r4+3][c] };
    *(bf16x4*)(d + (size_t)(c0 + c) * R + r0 + r4) = pk;
  }
}

// ============================ tiny serial kernels ============================
__global__ void k_finalize(int* __restrict__ meta, float* __restrict__ aux_out) {
  if (threadIdx.x == 0 && blockIdx.x == 0) {
    int acc = 0;
    for (int e = 0; e < 8; ++e) { meta[24 + e] = acc; acc += meta[8 + e]; }
    const float* probsum = (const float*)(meta + 32);
    const float* zsum    = (const float*)(meta + 40);
    float s = 0.f;
    for (int e = 0; e < 8; ++e)
      s += ((float)meta[e] * (1.f / 8192.f)) * (probsum[e] * (1.f / 8192.f));
    aux_out[0] = 8.f * s * 0.01f + (zsum[0] * (1.f / 8192.f)) * 0.001f;
  }
}

__global__ __launch_bounds__(256) void k_assign(
    const int* __restrict__ eidx, const float* __restrict__ gts,
    int* __restrict__ meta, int* __restrict__ list, float* __restrict__ gl)
{
  int t = blockIdx.x * 256 + threadIdx.x;
  int* cursor = meta + 16;
  const int* off = meta + 24;
  #pragma unroll
  for (int k = 0; k < 2; ++k) {
    int e = eidx[t*2 + k];
    int pos = atomicAdd(&cursor[e], 1);
    int slot = off[e] + pos;
    list[slot] = t;
    gl[slot] = gts[t*2 + k];
  }
}

// ===== grouped GEMM: 256x256 tile, BK=64, 8 waves, counted-vmcnt pipeline =====
// LDS (dynamic 128KB): buf p at p*65536: [A 256x64 bf16 | B at +32768].
// Row=128B=8 chunks of 16B; chunk c stored at c^(row&7) via pre-swizzled global src;
// frag reads apply the same XOR (measured zero bank conflicts R2/R3).
// Iter t: issue STAGE(t+1, buf^1) FIRST; s_waitcnt vmcnt(8) (t landed, t+1 flying);
// raw s_barrier; setprio(1)+64 MFMA; setprio(0); raw s_barrier. vmcnt(0) only at last tile.
// Hazards: RAW = own vmcnt + barrier (every wave waited own loads); WAR = ds_reads are
// consumed by MFMA (lgkmcnt before use) hence sampled before end-of-compute barrier.

// ============ GEMM1: H = gelu(Xn[list] @ W1t^T + b1), K=DM ============
__global__ __launch_bounds__(512, 2) void k_ffn1(
    const bf16_t* __restrict__ xn, const bf16_t* __restrict__ w1t,
    const float* __restrict__ b1, bf16_t* __restrict__ H,
    const int* __restrict__ list, const int* __restrict__ meta)
{
  extern __shared__ char smem[];
  // contiguous-per-XCD, m innermost: fixed (e,n) B-panel stays L2-resident
  int bid = blockIdx.x;
  int lin = (bid & 7) * 512 + (bid >> 3);
  int e = lin >> 9;
  int n = (lin >> 5) & 15;
  int m = lin & 31;

  int cnt = meta[8 + e];
  int m0 = m * 256;
  if (m0 >= cnt) return;
  int offe = meta[24 + e];
  int n0 = n * 256;

  int tid = threadIdx.x, lane = tid & 63, wv = tid >> 6;

  const bf16_t* sA[4]; const bf16_t* sB[4];
  unsigned dstA[4], dstB[4];
  #pragma unroll
  for (int i = 0; i < 4; ++i) {
    int q = i * 512 + tid;          // chunk-slot 0..2047
    int r = q >> 3;                 // row 0..255
    int c = (q & 7) ^ (r & 7);      // pre-swizzled source chunk
    int mrow = min(m0 + r, cnt - 1);
    int token = list[offe + mrow];
    sA[i] = xn + (size_t)token * DM + c * 8;
    sB[i] = w1t + ((size_t)e * DF + n0 + r) * DM + c * 8;
    dstA[i] = (unsigned)(i * 8192 + wv * 1024);
    dstB[i] = (unsigned)(32768 + i * 8192 + wv * 1024);
  }

  int wm = wv >> 2, wn = wv & 3;    // wave computes C[wm*128..+128][wn*64..+64]
  unsigned a_off[8], b_off[4];
  #pragma unroll
  for (int i = 0; i < 8; ++i) {
    int ra = wm * 128 + i * 16 + (lane & 15);
    a_off[i] = (unsigned)(ra * 128 + (((lane >> 4) ^ (ra & 7)) << 4));
  }
  #pragma unroll
  for (int j = 0; j < 4; ++j) {
    int rb = wn * 64 + j * 16 + (lane & 15);
    b_off[j] = (unsigned)(32768 + rb * 128 + (((lane >> 4) ^ (rb & 7)) << 4));
  }

  f32x4 acc[8][4];
  #pragma unroll
  for (int i = 0; i < 8; ++i)
    #pragma unroll
    for (int j = 0; j < 4; ++j)
      acc[i][j] = (f32x4){0.f, 0.f, 0.f, 0.f};

  // prologue: stage K-tile 0 into buf0
  #pragma unroll
  for (int i = 0; i < 4; ++i) {
    gload16(sA[i], smem + dstA[i]);
    gload16(sB[i], smem + dstB[i]);
  }

  unsigned roff = 0;
  for (int kt = 0; kt < NKT1; ++kt) {
    if (kt + 1 < NKT1) {
      unsigned poff = roff ^ 65536u;
      #pragma unroll
      for (int i = 0; i < 4; ++i) {
        gload16(sA[i] + (kt + 1) * 64, smem + poff + dstA[i]);
        gload16(sB[i] + (kt + 1) * 64, smem + poff + dstB[i]);
      }
      asm volatile("s_waitcnt vmcnt(8)" ::: "memory");
    } else {
      asm volatile("s_waitcnt vmcnt(0)" ::: "memory");
    }
    __builtin_amdgcn_sched_barrier(0);
    __builtin_amdgcn_s_barrier();
    __builtin_amdgcn_sched_barrier(0);

    bf16x8 bfrag[4][2];
    #pragma unroll
    for (int j = 0; j < 4; ++j)
      #pragma unroll
      for (int ks = 0; ks < 2; ++ks)
        bfrag[j][ks] = *(const bf16x8*)(smem + roff + (b_off[j] ^ (ks << 6)));
    __builtin_amdgcn_s_setprio(1);
    #pragma unroll
    for (int i = 0; i < 8; ++i) {
      bf16x8 af0 = *(const bf16x8*)(smem + roff + a_off[i]);
      bf16x8 af1 = *(const bf16x8*)(smem + roff + (a_off[i] ^ 64u));
      #pragma unroll
      for (int j = 0; j < 4; ++j) {
        acc[i][j] = mfma_bf16(af0, bfrag[j][0], acc[i][j]);
        acc[i][j] = mfma_bf16(af1, bfrag[j][1], acc[i][j]);
      }
    }
    __builtin_amdgcn_s_setprio(0);
    __builtin_amdgcn_sched_barrier(0);
    __builtin_amdgcn_s_barrier();
    __builtin_amdgcn_sched_barrier(0);
    roff ^= 65536u;
  }

  int rbase = wm * 128 + ((lane >> 4) << 2);
  int cbase = n0 + wn * 64 + (lane & 15);
  #pragma unroll
  for (int i = 0; i < 8; ++i) {
    #pragma unroll
    for (int q = 0; q < 4; ++q) {
      int mg = m0 + rbase + i * 16 + q;
      if (mg < cnt) {
        size_t hrow = (size_t)(offe + mg) * DF;
        #pragma unroll
        for (int j = 0; j < 4; ++j) {
          int col = cbase + j * 16;
          float hv = acc[i][j][q] + b1[e * DF + col];
          hv = 0.5f * hv * (1.f + erff(hv * 0.70710678118f));
          H[hrow + col] = (bf16_t)hv;
        }
      }
    }
  }
}

// ============ GEMM2: out += g * (H @ W2t^T + b2), K=DF ============
__global__ __launch_bounds__(512, 2) void k_ffn2(
    const bf16_t* __restrict__ H, const bf16_t* __restrict__ w2t,
    const float* __restrict__ b2, float* __restrict__ out,
    const int* __restrict__ list, const float* __restrict__ gl,
    const int* __restrict__ meta)
{
  extern __shared__ char smem[];
  int bid = blockIdx.x;
  int lin = (bid & 7) * 128 + (bid >> 3);
  int e = lin >> 7;
  int n = (lin >> 5) & 3;
  int m = lin & 31;

  int cnt = meta[8 + e];
  int m0 = m * 256;
  if (m0 >= cnt) return;
  int offe = meta[24 + e];
  int n0 = n * 256;

  int tid = threadIdx.x, lane = tid & 63, wv = tid >> 6;

  const bf16_t* sA[4]; const bf16_t* sB[4];
  unsigned dstA[4], dstB[4];
  #pragma unroll
  for (int i = 0; i < 4; ++i) {
    int q = i * 512 + tid;
    int r = q >> 3;
    int c = (q & 7) ^ (r & 7);
    int mrow = min(m0 + r, cnt - 1);
    sA[i] = H + (size_t)(offe + mrow) * DF + c * 8;
    sB[i] = w2t + ((size_t)e * DM + n0 + r) * DF + c * 8;
    dstA[i] = (unsigned)(i * 8192 + wv * 1024);
    dstB[i] = (unsigned)(32768 + i * 8192 + wv * 1024);
  }

  int wm = wv >> 2, wn = wv & 3;
  unsigned a_off[8], b_off[4];
  #pragma unroll
  for (int i = 0; i < 8; ++i) {
    int ra = wm * 128 + i * 16 + (lane & 15);
    a_off[i] = (unsigned)(ra * 128 + (((lane >> 4) ^ (ra & 7)) << 4));
  }
  #pragma unroll
  for (int j = 0; j < 4; ++j) {
    int rb = wn * 64 + j * 16 + (lane & 15);
    b_off[j] = (unsigned)(32768 + rb * 128 + (((lane >> 4) ^ (rb & 7)) << 4));
  }

  f32x4 acc[8][4];
  #pragma unroll
  for (int i = 0; i < 8; ++i)
    #pragma unroll
    for (int j = 0; j < 4; ++j)
      acc[i][j] = (f32x4){0.f, 0.f, 0.f, 0.f};

  #pragma unroll
  for (int i = 0; i < 4; ++i) {
    gload16(sA[i], smem + dstA[i]);
    gload16(sB[i], smem + dstB[i]);
  }

  unsigned roff = 0;
  for (int kt = 0; kt < NKT2; ++kt) {
    if (kt + 1 < NKT2) {
      unsigned poff = roff ^ 65536u;
      #pragma unroll
      for (int i = 0; i < 4; ++i) {
        gload16(sA[i] + (kt + 1) * 64, smem + poff + dstA[i]);
        gload16(sB[i] + (kt + 1) * 64, smem + poff + dstB[i]);
      }
      asm volatile("s_waitcnt vmcnt(8)" ::: "memory");
    } else {
      asm volatile("s_waitcnt vmcnt(0)" ::: "memory");
    }
    __builtin_amdgcn_sched_barrier(0);
    __builtin_amdgcn_s_barrier();
    __builtin_amdgcn_sched_barrier(0);

    bf16x8 bfrag[4][2];
    #pragma unroll
    for (int j = 0; j < 4; ++j)
      #pragma unroll
      for (int ks = 0; ks < 2; ++ks)
        bfrag[j][ks] = *(const bf16x8*)(smem + roff + (b_off[j] ^ (ks << 6)));
    __builtin_amdgcn_s_setprio(1);
    #pragma unroll
    for (int i = 0; i < 8; ++i) {
      bf16x8 af0 = *(const bf16x8*)(smem + roff + a_off[i]);
      bf16x8 af1 = *(const bf16x8*)(smem + roff + (a_off[i] ^ 64u));
      #pragma unroll
      for (int j = 0; j < 4; ++j) {
        acc[i][j] = mfma_bf16(af0, bfrag[j][0], acc[i][j]);
        acc[i][j] = mfma_bf16(af1, bfrag[j][1], acc[i][j]);
      }
    }
    __builtin_amdgcn_s_setprio(0);
    __builtin_amdgcn_sched_barrier(0);
    __builtin_amdgcn_s_barrier();
    __builtin_amdgcn_sched_barrier(0);
    roff ^= 65536u;
  }

  int rbase = wm * 128 + ((lane >> 4) << 2);
  int cbase = n0 + wn * 64 + (lane & 15);
  #pragma unroll
  for (int i = 0; i < 8; ++i) {
    #pragma unroll
    for (int q = 0; q < 4; ++q) {
      int mg = m0 + rbase + i * 16 + q;
      if (mg < cnt) {
        int slot = offe + mg;
        int token = list[slot];
        float g = gl[slot];
        size_t orow = (size_t)token * DM;
        #pragma unroll
        for (int j = 0; j < 4; ++j) {
          int col = cbase + j * 16;
          float yv = acc[i][j][q] + b2[e * DM + col];
          atomicAdd(&out[orow + col], g * yv);
        }
      }
    }
  }
}

// ============================ launch ============================
extern "C" void kernel_launch(void* const* d_in, const int* in_sizes, int n_in,
                              void* d_out, int out_size, void* d_ws, size_t ws_size,
                              hipStream_t stream) {
  const float* x      = (const float*)d_in[0];
  const float* gate_w = (const float*)d_in[1];
  const float* ln_g   = (const float*)d_in[2];
  const float* ln_b   = (const float*)d_in[3];
  const float* w1     = (const float*)d_in[4];
  const float* b1     = (const float*)d_in[5];
  const float* w2     = (const float*)d_in[6];
  const float* b2     = (const float*)d_in[7];
  float* out = (float*)d_out;

  char* ws = (char*)d_ws;
  bf16_t* xn   = (bf16_t*)(ws);                                  // 16 MiB
  bf16_t* w1t  = (bf16_t*)(ws + 16777216ull);                    // 64 MiB  [E][F][D]
  bf16_t* w2t  = (bf16_t*)(ws + 83886080ull);                    // 64 MiB  [E][D][F]
  bf16_t* H    = (bf16_t*)(ws + 150994944ull);                   // 128 MiB [NP][F]
  int*    list = (int*)   (ws + 285212672ull);
  float*  gl   = (float*) (ws + 285278208ull);
  int*    eidx = (int*)   (ws + 285343744ull);
  float*  gts  = (float*) (ws + 285409280ull);
  int*    meta = (int*)   (ws + 285474816ull);

  hipFuncSetAttribute((const void*)k_ffn1, hipFuncAttributeMaxDynamicSharedMemorySize, 131072);
  hipFuncSetAttribute((const void*)k_ffn2, hipFuncAttributeMaxDynamicSharedMemorySize, 131072);

  hipMemsetAsync(meta, 0, 256, stream);
  k_router<<<T_TOK / 4, 256, 0, stream>>>(x, gate_w, ln_g, ln_b, out, xn, eidx, gts, meta);
  k_convT<<<dim3(DF / 64, DM / 64, NE), 256, 0, stream>>>(w1, w1t, DM, DF);
  k_convT<<<dim3(DM / 64, DF / 64, NE), 256, 0, stream>>>(w2, w2t, DF, DM);
  k_finalize<<<1, 1, 0, stream>>>(meta, out + (size_t)T_TOK * DM);
  k_assign<<<T_TOK / 256, 256, 0, stream>>>(eidx, gts, meta, list, gl);
  k_ffn1<<<NE * 16 * 32, 512, 131072, stream>>>(xn, w1t, b1, H, list, meta);
  k_ffn2<<<NE * 4 * 32, 512, 131072, stream>>>(H, w2t, b2, out, list, gl, meta);
}

// Round 5
// 802.887 us; speedup vs baseline: 1.1337x; 1.1337x over previous
//
#include <hip/hip_runtime.h>
#include <math.h>

typedef __bf16 bf16_t;
typedef bf16_t bf16x8 __attribute__((ext_vector_type(8)));
typedef bf16_t bf16x4 __attribute__((ext_vector_type(4)));
typedef float  f32x4  __attribute__((ext_vector_type(4)));

#define T_TOK 8192
#define DM 1024
#define DF 4096
#define NE 8
#define NP 16384  // total token-expert pairs = T_TOK * 2

__device__ __forceinline__ f32x4 mfma_bf16(bf16x8 a, bf16x8 b, f32x4 c) {
  return __builtin_amdgcn_mfma_f32_16x16x32_bf16(a, b, c, 0, 0, 0);
}

__device__ __forceinline__ void gload16(const void* g, void* l) {
  __builtin_amdgcn_global_load_lds((const __attribute__((address_space(1))) void*)g,
                                   (__attribute__((address_space(3))) void*)l, 16, 0, 0);
}

// meta layout (ints): [0..7]=cnt1 [8..15]=cnt2 [16..23]=cursor [24..31]=off
// [32..39]=probsum(float) [40]=zsum(float)

// ============================ router ============================
__global__ __launch_bounds__(256) void k_router(
    const float* __restrict__ x, const float* __restrict__ gate_w,
    const float* __restrict__ ln_g, const float* __restrict__ ln_b,
    float* __restrict__ out, bf16_t* __restrict__ xn,
    int* __restrict__ eidx, float* __restrict__ gts, int* __restrict__ meta)
{
  int* cnt1 = meta;
  int* cnt2 = meta + 8;
  float* probsum = (float*)(meta + 32);
  float* zsum    = (float*)(meta + 40);

  __shared__ float sprob[8];
  __shared__ float sz;
  __shared__ int sc1[8], sc2[8];
  if (threadIdx.x < 8) { sprob[threadIdx.x] = 0.f; sc1[threadIdx.x] = 0; sc2[threadIdx.x] = 0; }
  if (threadIdx.x == 8) sz = 0.f;
  __syncthreads();

  int lane = threadIdx.x & 63, wv = threadIdx.x >> 6;
  int t = blockIdx.x * 4 + wv;
  const float* xt = x + (size_t)t * DM;

  float4 v[4];
  float s1 = 0.f, s2 = 0.f;
  #pragma unroll
  for (int c = 0; c < 4; ++c) {
    v[c] = *(const float4*)(xt + c * 256 + lane * 4);
    s1 += v[c].x + v[c].y + v[c].z + v[c].w;
    s2 += v[c].x * v[c].x + v[c].y * v[c].y + v[c].z * v[c].z + v[c].w * v[c].w;
  }
  #pragma unroll
  for (int o = 32; o > 0; o >>= 1) { s1 += __shfl_xor(s1, o, 64); s2 += __shfl_xor(s2, o, 64); }
  float mu = s1 * (1.f / DM);
  float var = s2 * (1.f / DM) - mu * mu;
  float rstd = rsqrtf(var + 1e-5f);

  float xv[16];
  #pragma unroll
  for (int c = 0; c < 4; ++c) {
    int d = c * 256 + lane * 4;
    float4 g4 = *(const float4*)(ln_g + d);
    float4 b4 = *(const float4*)(ln_b + d);
    xv[c*4+0] = (v[c].x - mu) * rstd * g4.x + b4.x;
    xv[c*4+1] = (v[c].y - mu) * rstd * g4.y + b4.y;
    xv[c*4+2] = (v[c].z - mu) * rstd * g4.z + b4.z;
    xv[c*4+3] = (v[c].w - mu) * rstd * g4.w + b4.w;
    *(float4*)(out + (size_t)t * DM + d) = v[c];  // residual init
    bf16x4 pk = { (bf16_t)xv[c*4+0], (bf16_t)xv[c*4+1], (bf16_t)xv[c*4+2], (bf16_t)xv[c*4+3] };
    *(bf16x4*)(xn + (size_t)t * DM + d) = pk;
  }

  float lg[8];
  #pragma unroll
  for (int e = 0; e < 8; ++e) {
    float p = 0.f;
    #pragma unroll
    for (int c = 0; c < 4; ++c) {
      int d = c * 256 + lane * 4;
      float4 g4 = *(const float4*)(gate_w + e * DM + d);
      p += xv[c*4+0] * g4.x + xv[c*4+1] * g4.y + xv[c*4+2] * g4.z + xv[c*4+3] * g4.w;
    }
    #pragma unroll
    for (int o = 32; o > 0; o >>= 1) p += __shfl_xor(p, o, 64);
    lg[e] = p;
  }

  if (lane == 0) {
    float m = -1e30f;
    #pragma unroll
    for (int e = 0; e < 8; ++e) { lg[e] = fminf(fmaxf(lg[e], -10.f), 10.f); m = fmaxf(m, lg[e]); }
    float pr[8]; float se = 0.f;
    #pragma unroll
    for (int e = 0; e < 8; ++e) { pr[e] = expf(lg[e] - m); se += pr[e]; }
    float inv = 1.f / se;
    #pragma unroll
    for (int e = 0; e < 8; ++e) pr[e] *= inv;
    float lse = m + logf(se);

    int e0 = 0; float p0 = pr[0];
    #pragma unroll
    for (int e = 1; e < 8; ++e) if (pr[e] > p0) { p0 = pr[e]; e0 = e; }
    int e1 = -1; float p1 = -1.f;
    #pragma unroll
    for (int e = 0; e < 8; ++e) if (e != e0 && pr[e] > p1) { p1 = pr[e]; e1 = e; }
    float s = p0 + p1 + 1e-8f;
    eidx[t*2]   = e0; eidx[t*2+1] = e1;
    gts[t*2]    = p0 / s; gts[t*2+1] = p1 / s;

    atomicAdd(&sc1[e0], 1);
    atomicAdd(&sc2[e0], 1);
    atomicAdd(&sc2[e1], 1);
    #pragma unroll
    for (int e = 0; e < 8; ++e) atomicAdd(&sprob[e], pr[e]);
    atomicAdd(&sz, lse * lse);
  }
  __syncthreads();
  if (threadIdx.x < 8) {
    if (sc1[threadIdx.x]) atomicAdd(&cnt1[threadIdx.x], sc1[threadIdx.x]);
    if (sc2[threadIdx.x]) atomicAdd(&cnt2[threadIdx.x], sc2[threadIdx.x]);
    atomicAdd(&probsum[threadIdx.x], sprob[threadIdx.x]);
  }
  if (threadIdx.x == 8) atomicAdd(zsum, sz);
}

// ========== weight convert + transpose: src [R][C] fp32 -> dst [C][R] bf16 ==========
__global__ __launch_bounds__(256) void k_convT(
    const float* __restrict__ src, bf16_t* __restrict__ dst, int R, int C)
{
  __shared__ float tile[64][65];
  int e = blockIdx.z;
  const float* s = src + (size_t)e * R * C;
  bf16_t* d = dst + (size_t)e * R * C;
  int c0 = blockIdx.x * 64, r0 = blockIdx.y * 64;
  int t = threadIdx.x;
  #pragma unroll
  for (int i = 0; i < 4; ++i) {
    int idx = i * 256 + t;
    int r = idx >> 4, c4 = (idx & 15) * 4;
    float4 v = *(const float4*)(s + (size_t)(r0 + r) * C + c0 + c4);
    tile[r][c4]   = v.x; tile[r][c4+1] = v.y;
    tile[r][c4+2] = v.z; tile[r][c4+3] = v.w;
  }
  __syncthreads();
  #pragma unroll
  for (int i = 0; i < 4; ++i) {
    int idx = i * 256 + t;
    int c = idx >> 4, r4 = (idx & 15) * 4;
    bf16x4 pk = { (bf16_t)tile[r4][c], (bf16_t)tile[r4+1][c],
                  (bf16_t)tile[r4+2][c], (bf16_t)tile[r4+3][c] };
    *(bf16x4*)(d + (size_t)(c0 + c) * R + r0 + r4) = pk;
  }
}

// ============================ tiny serial kernels ============================
__global__ void k_finalize(int* __restrict__ meta, float* __restrict__ aux_out) {
  if (threadIdx.x == 0 && blockIdx.x == 0) {
    int acc = 0;
    for (int e = 0; e < 8; ++e) { meta[24 + e] = acc; acc += meta[8 + e]; }
    const float* probsum = (const float*)(meta + 32);
    const float* zsum    = (const float*)(meta + 40);
    float s = 0.f;
    for (int e = 0; e < 8; ++e)
      s += ((float)meta[e] * (1.f / 8192.f)) * (probsum[e] * (1.f / 8192.f));
    aux_out[0] = 8.f * s * 0.01f + (zsum[0] * (1.f / 8192.f)) * 0.001f;
  }
}

// k_assign: slot assignment; also records token->slot map (t2s aliases gts buffer:
// gts[t*2+k] is read into a register BEFORE t2s[t*2+k] is written by the same thread).
__global__ __launch_bounds__(256) void k_assign(
    const int* __restrict__ eidx, float* __restrict__ gts,
    int* __restrict__ meta, int* __restrict__ list, float* __restrict__ gl,
    int* __restrict__ t2s)
{
  int t = blockIdx.x * 256 + threadIdx.x;
  int* cursor = meta + 16;
  const int* off = meta + 24;
  #pragma unroll
  for (int k = 0; k < 2; ++k) {
    int e = eidx[t*2 + k];
    float g = gts[t*2 + k];          // read before aliased write
    int pos = atomicAdd(&cursor[e], 1);
    int slot = off[e] + pos;
    list[slot] = t;
    gl[slot] = g;
    t2s[t*2 + k] = slot;
  }
}

// ===== GEMM1 (R1-proven m97 skeleton): 128x128, BK=32, 4 waves, 16KB single-buf =====
// LDS: A [128 rows][32 k] bf16 at 0 (8KB), B at 8192. Row=64B=4 chunks of 16B,
// chunk c stored at c^(row&3) via pre-swizzled global source; frag read applies same XOR
// (residual 4-way conflict accepted -- R1-measured benign at this occupancy).
__global__ __launch_bounds__(256) void k_ffn1(
    const bf16_t* __restrict__ xn, const bf16_t* __restrict__ w1t,
    const float* __restrict__ b1, bf16_t* __restrict__ H,
    const int* __restrict__ list, const int* __restrict__ meta)
{
  int e = blockIdx.z;
  int cnt = meta[8 + e];
  int m0 = blockIdx.y * 128;
  if (m0 >= cnt) return;
  int offe = meta[24 + e];
  int n0 = blockIdx.x * 128;

  __shared__ __align__(1024) char smem[16384];
  int tid = threadIdx.x, lane = tid & 63, wv = tid >> 6;

  const bf16_t* srcA[2]; const bf16_t* srcB[2];
  unsigned ldso[2];
  #pragma unroll
  for (int r = 0; r < 2; ++r) {
    int q = r * 256 + tid;           // 16B-chunk slot 0..511
    int row = q >> 2;
    int ch = (q & 3) ^ (row & 3);    // pre-swizzled global source chunk
    int mrow = min(m0 + row, cnt - 1);
    int token = list[offe + mrow];
    srcA[r] = xn + (size_t)token * DM + ch * 8;
    srcB[r] = w1t + ((size_t)e * DF + n0 + row) * DM + ch * 8;
    ldso[r] = (unsigned)(r * 4096 + wv * 1024);   // wave-uniform LDS base
  }

  int fr = (wv >> 1) * 64 + (lane & 15);
  int fc = (wv & 1) * 64 + (lane & 15);
  unsigned a_off[4], b_off[4];
  #pragma unroll
  for (int i = 0; i < 4; ++i) {
    int ra = fr + i * 16, rb = fc + i * 16;
    a_off[i] = (unsigned)(ra * 64 + (((lane >> 4) ^ (ra & 3)) << 4));
    b_off[i] = (unsigned)(8192 + rb * 64 + (((lane >> 4) ^ (rb & 3)) << 4));
  }

  f32x4 acc[4][4];
  #pragma unroll
  for (int i = 0; i < 4; ++i)
    #pragma unroll
    for (int j = 0; j < 4; ++j)
      acc[i][j] = (f32x4){0.f, 0.f, 0.f, 0.f};

  for (int kt = 0; kt < DM / 32; ++kt) {
    #pragma unroll
    for (int r = 0; r < 2; ++r) {
      gload16(srcA[r] + kt * 32, smem + ldso[r]);
      gload16(srcB[r] + kt * 32, smem + 8192 + ldso[r]);
    }
    __syncthreads();
    bf16x8 af[4], bfr[4];
    #pragma unroll
    for (int i = 0; i < 4; ++i) af[i]  = *(const bf16x8*)(smem + a_off[i]);
    #pragma unroll
    for (int i = 0; i < 4; ++i) bfr[i] = *(const bf16x8*)(smem + b_off[i]);
    #pragma unroll
    for (int i = 0; i < 4; ++i)
      #pragma unroll
      for (int j = 0; j < 4; ++j)
        acc[i][j] = mfma_bf16(af[i], bfr[j], acc[i][j]);
    __syncthreads();
  }

  int rbase = (wv >> 1) * 64 + ((lane >> 4) << 2);
  int cbase = n0 + (wv & 1) * 64 + (lane & 15);
  #pragma unroll
  for (int i = 0; i < 4; ++i) {
    #pragma unroll
    for (int q = 0; q < 4; ++q) {
      int mg = m0 + rbase + i * 16 + q;
      if (mg < cnt) {
        size_t hrow = (size_t)(offe + mg) * DF;
        #pragma unroll
        for (int j = 0; j < 4; ++j) {
          int col = cbase + j * 16;
          float hv = acc[i][j][q] + b1[e * DF + col];
          hv = 0.5f * hv * (1.f + erff(hv * 0.70710678118f));
          H[hrow + col] = (bf16_t)hv;
        }
      }
    }
  }
}

// ===== GEMM2: Y[slot] = H[slot] @ W2t^T + b2 (fp32, NO atomics, NO gather) =====
// 128x256 tile, BK=32, 8 waves (512 thr), 24KB single-buf. A rows (H slots) contiguous.
// Waves: wm = wv>>2 (2 m-halves), wn = wv&3 (4 n-quarters); per-wave out 64x64.
__global__ __launch_bounds__(512) void k_ffn2(
    const bf16_t* __restrict__ H, const bf16_t* __restrict__ w2t,
    const float* __restrict__ b2, float* __restrict__ Y,
    const int* __restrict__ meta)
{
  int e = blockIdx.z;
  int cnt = meta[8 + e];
  int m0 = blockIdx.y * 128;
  if (m0 >= cnt) return;
  int offe = meta[24 + e];
  int n0 = blockIdx.x * 256;

  __shared__ __align__(1024) char smem[24576];
  int tid = threadIdx.x, lane = tid & 63, wv = tid >> 6;

  // A: 128 rows x 32k = 512 chunk-slots (1/thread); B: 256 rows x 32k = 1024 (2/thread)
  const bf16_t* srcA; const bf16_t* srcB[2];
  {
    int q = tid;
    int row = q >> 2;
    int ch = (q & 3) ^ (row & 3);
    int mrow = min(m0 + row, cnt - 1);
    srcA = H + (size_t)(offe + mrow) * DF + ch * 8;
  }
  #pragma unroll
  for (int i = 0; i < 2; ++i) {
    int q = i * 512 + tid;
    int row = q >> 2;
    int ch = (q & 3) ^ (row & 3);
    srcB[i] = w2t + ((size_t)e * DM + n0 + row) * DF + ch * 8;
  }
  unsigned dA = (unsigned)(wv * 1024);
  unsigned dB0 = (unsigned)(8192 + wv * 1024);
  unsigned dB1 = (unsigned)(16384 + wv * 1024);

  int wm = wv >> 2, wn = wv & 3;
  unsigned a_off[4], b_off[4];
  #pragma unroll
  for (int i = 0; i < 4; ++i) {
    int ra = wm * 64 + i * 16 + (lane & 15);
    a_off[i] = (unsigned)(ra * 64 + (((lane >> 4) ^ (ra & 3)) << 4));
  }
  #pragma unroll
  for (int j = 0; j < 4; ++j) {
    int rb = wn * 64 + j * 16 + (lane & 15);
    b_off[j] = (unsigned)(8192 + rb * 64 + (((lane >> 4) ^ (rb & 3)) << 4));
  }

  f32x4 acc[4][4];
  #pragma unroll
  for (int i = 0; i < 4; ++i)
    #pragma unroll
    for (int j = 0; j < 4; ++j)
      acc[i][j] = (f32x4){0.f, 0.f, 0.f, 0.f};

  for (int kt = 0; kt < DF / 32; ++kt) {
    gload16(srcA + kt * 32, smem + dA);
    gload16(srcB[0] + kt * 32, smem + dB0);
    gload16(srcB[1] + kt * 32, smem + dB1);
    __syncthreads();
    bf16x8 af[4], bfr[4];
    #pragma unroll
    for (int i = 0; i < 4; ++i) af[i]  = *(const bf16x8*)(smem + a_off[i]);
    #pragma unroll
    for (int j = 0; j < 4; ++j) bfr[j] = *(const bf16x8*)(smem + b_off[j]);
    #pragma unroll
    for (int i = 0; i < 4; ++i)
      #pragma unroll
      for (int j = 0; j < 4; ++j)
        acc[i][j] = mfma_bf16(af[i], bfr[j], acc[i][j]);
    __syncthreads();
  }

  int rbase = wm * 64 + ((lane >> 4) << 2);
  int cbase = n0 + wn * 64 + (lane & 15);
  #pragma unroll
  for (int i = 0; i < 4; ++i) {
    #pragma unroll
    for (int q = 0; q < 4; ++q) {
      int mg = m0 + rbase + i * 16 + q;
      if (mg < cnt) {
        size_t yrow = (size_t)(offe + mg) * DM;
        #pragma unroll
        for (int j = 0; j < 4; ++j) {
          int col = cbase + j * 16;
          Y[yrow + col] = acc[i][j][q] + b2[e * DM + col];
        }
      }
    }
  }
}

// ===== combine: out[t] += g0*Y[s0] + g1*Y[s1] (one wave per token) =====
__global__ __launch_bounds__(256) void k_combine(
    const float* __restrict__ Y, const int* __restrict__ t2s,
    const float* __restrict__ gl, float* __restrict__ out)
{
  int lane = threadIdx.x & 63, wv = threadIdx.x >> 6;
  int t = blockIdx.x * 4 + wv;
  int s0 = t2s[t*2], s1 = t2s[t*2 + 1];
  float g0 = gl[s0], g1 = gl[s1];
  const float* y0 = Y + (size_t)s0 * DM;
  const float* y1 = Y + (size_t)s1 * DM;
  float* o = out + (size_t)t * DM;
  #pragma unroll
  for (int c = 0; c < 4; ++c) {
    int d = c * 256 + lane * 4;
    float4 r  = *(const float4*)(o + d);
    float4 a  = *(const float4*)(y0 + d);
    float4 b  = *(const float4*)(y1 + d);
    r.x += g0 * a.x + g1 * b.x;
    r.y += g0 * a.y + g1 * b.y;
    r.z += g0 * a.z + g1 * b.z;
    r.w += g0 * a.w + g1 * b.w;
    *(float4*)(o + d) = r;
  }
}

// ============================ launch ============================
extern "C" void kernel_launch(void* const* d_in, const int* in_sizes, int n_in,
                              void* d_out, int out_size, void* d_ws, size_t ws_size,
                              hipStream_t stream) {
  const float* x      = (const float*)d_in[0];
  const float* gate_w = (const float*)d_in[1];
  const float* ln_g   = (const float*)d_in[2];
  const float* ln_b   = (const float*)d_in[3];
  const float* w1     = (const float*)d_in[4];
  const float* b1     = (const float*)d_in[5];
  const float* w2     = (const float*)d_in[6];
  const float* b2     = (const float*)d_in[7];
  float* out = (float*)d_out;

  char* ws = (char*)d_ws;
  bf16_t* xn   = (bf16_t*)(ws);                                  // 16 MiB
  bf16_t* w1t  = (bf16_t*)(ws + 16777216ull);                    // 64 MiB [E][F][D]; dead after ffn1
  float*  Y    = (float*) (ws + 16777216ull);                    //   reused: Y [NP][DM] fp32 (exact fit)
  bf16_t* w2t  = (bf16_t*)(ws + 83886080ull);                    // 64 MiB [E][D][F]
  bf16_t* H    = (bf16_t*)(ws + 150994944ull);                   // 128 MiB [NP][F]
  int*    list = (int*)   (ws + 285212672ull);
  float*  gl   = (float*) (ws + 285278208ull);
  int*    eidx = (int*)   (ws + 285343744ull);
  float*  gts  = (float*) (ws + 285409280ull);                   // aliased as t2s after k_assign
  int*    t2s  = (int*)   (ws + 285409280ull);
  int*    meta = (int*)   (ws + 285474816ull);

  hipMemsetAsync(meta, 0, 256, stream);
  k_router<<<T_TOK / 4, 256, 0, stream>>>(x, gate_w, ln_g, ln_b, out, xn, eidx, gts, meta);
  k_convT<<<dim3(DF / 64, DM / 64, NE), 256, 0, stream>>>(w1, w1t, DM, DF);
  k_convT<<<dim3(DM / 64, DF / 64, NE), 256, 0, stream>>>(w2, w2t, DF, DM);
  k_finalize<<<1, 1, 0, stream>>>(meta, out + (size_t)T_TOK * DM);
  k_assign<<<T_TOK / 256, 256, 0, stream>>>(eidx, gts, meta, list, gl, t2s);
  k_ffn1<<<dim3(DF / 128, 64, NE), 256, 0, stream>>>(xn, w1t, b1, H, list, meta);
  k_ffn2<<<dim3(DM / 256, 64, NE), 512, 0, stream>>>(H, w2t, b2, Y, meta);
  k_combine<<<T_TOK / 4, 256, 0, stream>>>(Y, t2s, gl, out);
}

// Round 6
// 703.485 us; speedup vs baseline: 1.2939x; 1.1413x over previous
//
#include <hip/hip_runtime.h>
#include <math.h>

typedef __bf16 bf16_t;
typedef bf16_t bf16x8 __attribute__((ext_vector_type(8)));
typedef bf16_t bf16x4 __attribute__((ext_vector_type(4)));
typedef float  f32x4  __attribute__((ext_vector_type(4)));

#define T_TOK 8192
#define DM 1024
#define DF 4096
#define NE 8
#define NP 16384  // total token-expert pairs = T_TOK * 2

__device__ __forceinline__ f32x4 mfma_bf16(bf16x8 a, bf16x8 b, f32x4 c) {
  return __builtin_amdgcn_mfma_f32_16x16x32_bf16(a, b, c, 0, 0, 0);
}

__device__ __forceinline__ void gload16(const void* g, void* l) {
  __builtin_amdgcn_global_load_lds((const __attribute__((address_space(1))) void*)g,
                                   (__attribute__((address_space(3))) void*)l, 16, 0, 0);
}

// Abramowitz-Stegun 7.1.26 erf, |err| <= 1.5e-7, ~12 VALU ops (vs erff libcall)
__device__ __forceinline__ float erf_fast(float x) {
  float ax = fabsf(x);
  float t = 1.f / (1.f + 0.3275911f * ax);
  float p = t * (0.254829592f + t * (-0.284496736f + t * (1.421413741f +
            t * (-1.453152027f + t * 1.061405429f))));
  float r = 1.f - p * __expf(-ax * ax);
  return copysignf(r, x);
}

// meta layout (ints): [0..7]=cnt1 [8..15]=cnt2 [16..23]=cursor [24..31]=off
// [32..39]=probsum(float) [40]=zsum(float)

// ============================ router ============================
__global__ __launch_bounds__(256) void k_router(
    const float* __restrict__ x, const float* __restrict__ gate_w,
    const float* __restrict__ ln_g, const float* __restrict__ ln_b,
    float* __restrict__ out, bf16_t* __restrict__ xn,
    int* __restrict__ eidx, float* __restrict__ gts, int* __restrict__ meta)
{
  int* cnt1 = meta;
  int* cnt2 = meta + 8;
  float* probsum = (float*)(meta + 32);
  float* zsum    = (float*)(meta + 40);

  __shared__ float sprob[8];
  __shared__ float sz;
  __shared__ int sc1[8], sc2[8];
  if (threadIdx.x < 8) { sprob[threadIdx.x] = 0.f; sc1[threadIdx.x] = 0; sc2[threadIdx.x] = 0; }
  if (threadIdx.x == 8) sz = 0.f;
  __syncthreads();

  int lane = threadIdx.x & 63, wv = threadIdx.x >> 6;
  int t = blockIdx.x * 4 + wv;
  const float* xt = x + (size_t)t * DM;

  float4 v[4];
  float s1 = 0.f, s2 = 0.f;
  #pragma unroll
  for (int c = 0; c < 4; ++c) {
    v[c] = *(const float4*)(xt + c * 256 + lane * 4);
    s1 += v[c].x + v[c].y + v[c].z + v[c].w;
    s2 += v[c].x * v[c].x + v[c].y * v[c].y + v[c].z * v[c].z + v[c].w * v[c].w;
  }
  #pragma unroll
  for (int o = 32; o > 0; o >>= 1) { s1 += __shfl_xor(s1, o, 64); s2 += __shfl_xor(s2, o, 64); }
  float mu = s1 * (1.f / DM);
  float var = s2 * (1.f / DM) - mu * mu;
  float rstd = rsqrtf(var + 1e-5f);

  float xv[16];
  #pragma unroll
  for (int c = 0; c < 4; ++c) {
    int d = c * 256 + lane * 4;
    float4 g4 = *(const float4*)(ln_g + d);
    float4 b4 = *(const float4*)(ln_b + d);
    xv[c*4+0] = (v[c].x - mu) * rstd * g4.x + b4.x;
    xv[c*4+1] = (v[c].y - mu) * rstd * g4.y + b4.y;
    xv[c*4+2] = (v[c].z - mu) * rstd * g4.z + b4.z;
    xv[c*4+3] = (v[c].w - mu) * rstd * g4.w + b4.w;
    *(float4*)(out + (size_t)t * DM + d) = v[c];  // residual init
    bf16x4 pk = { (bf16_t)xv[c*4+0], (bf16_t)xv[c*4+1], (bf16_t)xv[c*4+2], (bf16_t)xv[c*4+3] };
    *(bf16x4*)(xn + (size_t)t * DM + d) = pk;
  }

  float lg[8];
  #pragma unroll
  for (int e = 0; e < 8; ++e) {
    float p = 0.f;
    #pragma unroll
    for (int c = 0; c < 4; ++c) {
      int d = c * 256 + lane * 4;
      float4 g4 = *(const float4*)(gate_w + e * DM + d);
      p += xv[c*4+0] * g4.x + xv[c*4+1] * g4.y + xv[c*4+2] * g4.z + xv[c*4+3] * g4.w;
    }
    #pragma unroll
    for (int o = 32; o > 0; o >>= 1) p += __shfl_xor(p, o, 64);
    lg[e] = p;
  }

  if (lane == 0) {
    float m = -1e30f;
    #pragma unroll
    for (int e = 0; e < 8; ++e) { lg[e] = fminf(fmaxf(lg[e], -10.f), 10.f); m = fmaxf(m, lg[e]); }
    float pr[8]; float se = 0.f;
    #pragma unroll
    for (int e = 0; e < 8; ++e) { pr[e] = expf(lg[e] - m); se += pr[e]; }
    float inv = 1.f / se;
    #pragma unroll
    for (int e = 0; e < 8; ++e) pr[e] *= inv;
    float lse = m + logf(se);

    int e0 = 0; float p0 = pr[0];
    #pragma unroll
    for (int e = 1; e < 8; ++e) if (pr[e] > p0) { p0 = pr[e]; e0 = e; }
    int e1 = -1; float p1 = -1.f;
    #pragma unroll
    for (int e = 0; e < 8; ++e) if (e != e0 && pr[e] > p1) { p1 = pr[e]; e1 = e; }
    float s = p0 + p1 + 1e-8f;
    eidx[t*2]   = e0; eidx[t*2+1] = e1;
    gts[t*2]    = p0 / s; gts[t*2+1] = p1 / s;

    atomicAdd(&sc1[e0], 1);
    atomicAdd(&sc2[e0], 1);
    atomicAdd(&sc2[e1], 1);
    #pragma unroll
    for (int e = 0; e < 8; ++e) atomicAdd(&sprob[e], pr[e]);
    atomicAdd(&sz, lse * lse);
  }
  __syncthreads();
  if (threadIdx.x < 8) {
    if (sc1[threadIdx.x]) atomicAdd(&cnt1[threadIdx.x], sc1[threadIdx.x]);
    if (sc2[threadIdx.x]) atomicAdd(&cnt2[threadIdx.x], sc2[threadIdx.x]);
    atomicAdd(&probsum[threadIdx.x], sprob[threadIdx.x]);
  }
  if (threadIdx.x == 8) atomicAdd(zsum, sz);
}

// ========== weight convert + transpose: src [R][C] fp32 -> dst [C][R] bf16 ==========
__global__ __launch_bounds__(256) void k_convT(
    const float* __restrict__ src, bf16_t* __restrict__ dst, int R, int C)
{
  __shared__ float tile[64][65];
  int e = blockIdx.z;
  const float* s = src + (size_t)e * R * C;
  bf16_t* d = dst + (size_t)e * R * C;
  int c0 = blockIdx.x * 64, r0 = blockIdx.y * 64;
  int t = threadIdx.x;
  #pragma unroll
  for (int i = 0; i < 4; ++i) {
    int idx = i * 256 + t;
    int r = idx >> 4, c4 = (idx & 15) * 4;
    float4 v = *(const float4*)(s + (size_t)(r0 + r) * C + c0 + c4);
    tile[r][c4]   = v.x; tile[r][c4+1] = v.y;
    tile[r][c4+2] = v.z; tile[r][c4+3] = v.w;
  }
  __syncthreads();
  #pragma unroll
  for (int i = 0; i < 4; ++i) {
    int idx = i * 256 + t;
    int c = idx >> 4, r4 = (idx & 15) * 4;
    bf16x4 pk = { (bf16_t)tile[r4][c], (bf16_t)tile[r4+1][c],
                  (bf16_t)tile[r4+2][c], (bf16_t)tile[r4+3][c] };
    *(bf16x4*)(d + (size_t)(c0 + c) * R + r0 + r4) = pk;
  }
}

// ============================ tiny serial kernels ============================
__global__ void k_finalize(int* __restrict__ meta, float* __restrict__ aux_out) {
  if (threadIdx.x == 0 && blockIdx.x == 0) {
    int acc = 0;
    for (int e = 0; e < 8; ++e) { meta[24 + e] = acc; acc += meta[8 + e]; }
    const float* probsum = (const float*)(meta + 32);
    const float* zsum    = (const float*)(meta + 40);
    float s = 0.f;
    for (int e = 0; e < 8; ++e)
      s += ((float)meta[e] * (1.f / 8192.f)) * (probsum[e] * (1.f / 8192.f));
    aux_out[0] = 8.f * s * 0.01f + (zsum[0] * (1.f / 8192.f)) * 0.001f;
  }
}

__global__ __launch_bounds__(256) void k_assign(
    const int* __restrict__ eidx, float* __restrict__ gts,
    int* __restrict__ meta, int* __restrict__ list, float* __restrict__ gl,
    int* __restrict__ t2s)
{
  int t = blockIdx.x * 256 + threadIdx.x;
  int* cursor = meta + 16;
  const int* off = meta + 24;
  #pragma unroll
  for (int k = 0; k < 2; ++k) {
    int e = eidx[t*2 + k];
    float g = gts[t*2 + k];          // read before aliased write
    int pos = atomicAdd(&cursor[e], 1);
    int slot = off[e] + pos;
    list[slot] = t;
    gl[slot] = g;
    t2s[t*2 + k] = slot;
  }
}

// ===== GEMM1: 128x128, BK=32, 4 waves, DBUF 2x16KB, 1 barrier/tile =====
// Per K-tile: issue STAGE(kt+1 -> buf^1) FIRST, then ds_read+MFMA on buf, then ONE
// __syncthreads (its implicit vmcnt(0) drains the prefetch AFTER compute overlapped it).
// RAW: barrier implies all waves' stage landed. WAR: buf^1's readers finished lgkmcnt(0)
// before the prior barrier. Swizzle: chunk c at c^(row&3) (residual 4-way accepted, R1/R5).
__global__ __launch_bounds__(256) void k_ffn1(
    const bf16_t* __restrict__ xn, const bf16_t* __restrict__ w1t,
    const float* __restrict__ b1, bf16_t* __restrict__ H,
    const int* __restrict__ list, const int* __restrict__ meta)
{
  int e = blockIdx.z;
  int cnt = meta[8 + e];
  int m0 = blockIdx.y * 128;
  if (m0 >= cnt) return;
  int offe = meta[24 + e];
  int n0 = blockIdx.x * 128;

  __shared__ __align__(1024) char smem[32768];
  int tid = threadIdx.x, lane = tid & 63, wv = tid >> 6;

  const bf16_t* srcA[2]; const bf16_t* srcB[2];
  unsigned ldso[2];
  #pragma unroll
  for (int r = 0; r < 2; ++r) {
    int q = r * 256 + tid;           // 16B-chunk slot 0..511
    int row = q >> 2;
    int ch = (q & 3) ^ (row & 3);    // pre-swizzled global source chunk
    int mrow = min(m0 + row, cnt - 1);
    int token = list[offe + mrow];
    srcA[r] = xn + (size_t)token * DM + ch * 8;
    srcB[r] = w1t + ((size_t)e * DF + n0 + row) * DM + ch * 8;
    ldso[r] = (unsigned)(r * 4096 + wv * 1024);   // wave-uniform LDS base
  }

  int fr = (wv >> 1) * 64 + (lane & 15);
  int fc = (wv & 1) * 64 + (lane & 15);
  unsigned a_off[4], b_off[4];
  #pragma unroll
  for (int i = 0; i < 4; ++i) {
    int ra = fr + i * 16, rb = fc + i * 16;
    a_off[i] = (unsigned)(ra * 64 + (((lane >> 4) ^ (ra & 3)) << 4));
    b_off[i] = (unsigned)(8192 + rb * 64 + (((lane >> 4) ^ (rb & 3)) << 4));
  }

  f32x4 acc[4][4];
  #pragma unroll
  for (int i = 0; i < 4; ++i)
    #pragma unroll
    for (int j = 0; j < 4; ++j)
      acc[i][j] = (f32x4){0.f, 0.f, 0.f, 0.f};

  // prologue: stage K-tile 0 into buf0
  #pragma unroll
  for (int r = 0; r < 2; ++r) {
    gload16(srcA[r], smem + ldso[r]);
    gload16(srcB[r], smem + 8192 + ldso[r]);
  }
  __syncthreads();

  unsigned roff = 0;
  for (int kt = 0; kt < DM / 32; ++kt) {
    if (kt + 1 < DM / 32) {
      unsigned poff = roff ^ 16384u;
      #pragma unroll
      for (int r = 0; r < 2; ++r) {
        gload16(srcA[r] + (kt + 1) * 32, smem + poff + ldso[r]);
        gload16(srcB[r] + (kt + 1) * 32, smem + poff + 8192 + ldso[r]);
      }
    }
    bf16x8 af[4], bfr[4];
    #pragma unroll
    for (int i = 0; i < 4; ++i) af[i]  = *(const bf16x8*)(smem + roff + a_off[i]);
    #pragma unroll
    for (int i = 0; i < 4; ++i) bfr[i] = *(const bf16x8*)(smem + roff + b_off[i]);
    #pragma unroll
    for (int i = 0; i < 4; ++i)
      #pragma unroll
      for (int j = 0; j < 4; ++j)
        acc[i][j] = mfma_bf16(af[i], bfr[j], acc[i][j]);
    __syncthreads();   // one barrier/tile: drains prefetch (vmcnt 0) + lgkmcnt
    roff ^= 16384u;
  }

  int rbase = (wv >> 1) * 64 + ((lane >> 4) << 2);
  int cbase = n0 + (wv & 1) * 64 + (lane & 15);
  #pragma unroll
  for (int i = 0; i < 4; ++i) {
    #pragma unroll
    for (int q = 0; q < 4; ++q) {
      int mg = m0 + rbase + i * 16 + q;
      if (mg < cnt) {
        size_t hrow = (size_t)(offe + mg) * DF;
        #pragma unroll
        for (int j = 0; j < 4; ++j) {
          int col = cbase + j * 16;
          float hv = acc[i][j][q] + b1[e * DF + col];
          hv = 0.5f * hv * (1.f + erf_fast(hv * 0.70710678118f));
          H[hrow + col] = (bf16_t)hv;
        }
      }
    }
  }
}

// ===== GEMM2: Y[slot] = H[slot] @ W2t^T + b2 (bf16 out, no atomics) =====
// 128x256, BK=32, 8 waves, DBUF 2x24KB (48KB), same 1-barrier prefetch loop.
__global__ __launch_bounds__(512) void k_ffn2(
    const bf16_t* __restrict__ H, const bf16_t* __restrict__ w2t,
    const float* __restrict__ b2, bf16_t* __restrict__ Y,
    const int* __restrict__ meta)
{
  int e = blockIdx.z;
  int cnt = meta[8 + e];
  int m0 = blockIdx.y * 128;
  if (m0 >= cnt) return;
  int offe = meta[24 + e];
  int n0 = blockIdx.x * 256;

  __shared__ __align__(1024) char smem[49152];
  int tid = threadIdx.x, lane = tid & 63, wv = tid >> 6;

  const bf16_t* srcA; const bf16_t* srcB[2];
  {
    int q = tid;
    int row = q >> 2;
    int ch = (q & 3) ^ (row & 3);
    int mrow = min(m0 + row, cnt - 1);
    srcA = H + (size_t)(offe + mrow) * DF + ch * 8;
  }
  #pragma unroll
  for (int i = 0; i < 2; ++i) {
    int q = i * 512 + tid;
    int row = q >> 2;
    int ch = (q & 3) ^ (row & 3);
    srcB[i] = w2t + ((size_t)e * DM + n0 + row) * DF + ch * 8;
  }
  unsigned dA  = (unsigned)(wv * 1024);
  unsigned dB0 = (unsigned)(8192 + wv * 1024);
  unsigned dB1 = (unsigned)(16384 + wv * 1024);

  int wm = wv >> 2, wn = wv & 3;
  unsigned a_off[4], b_off[4];
  #pragma unroll
  for (int i = 0; i < 4; ++i) {
    int ra = wm * 64 + i * 16 + (lane & 15);
    a_off[i] = (unsigned)(ra * 64 + (((lane >> 4) ^ (ra & 3)) << 4));
  }
  #pragma unroll
  for (int j = 0; j < 4; ++j) {
    int rb = wn * 64 + j * 16 + (lane & 15);
    b_off[j] = (unsigned)(8192 + rb * 64 + (((lane >> 4) ^ (rb & 3)) << 4));
  }

  f32x4 acc[4][4];
  #pragma unroll
  for (int i = 0; i < 4; ++i)
    #pragma unroll
    for (int j = 0; j < 4; ++j)
      acc[i][j] = (f32x4){0.f, 0.f, 0.f, 0.f};

  // prologue
  gload16(srcA, smem + dA);
  gload16(srcB[0], smem + dB0);
  gload16(srcB[1], smem + dB1);
  __syncthreads();

  unsigned roff = 0;
  for (int kt = 0; kt < DF / 32; ++kt) {
    if (kt + 1 < DF / 32) {
      unsigned poff = roff ^ 24576u;
      gload16(srcA + (kt + 1) * 32, smem + poff + dA);
      gload16(srcB[0] + (kt + 1) * 32, smem + poff + dB0);
      gload16(srcB[1] + (kt + 1) * 32, smem + poff + dB1);
    }
    bf16x8 af[4], bfr[4];
    #pragma unroll
    for (int i = 0; i < 4; ++i) af[i]  = *(const bf16x8*)(smem + roff + a_off[i]);
    #pragma unroll
    for (int j = 0; j < 4; ++j) bfr[j] = *(const bf16x8*)(smem + roff + b_off[j]);
    #pragma unroll
    for (int i = 0; i < 4; ++i)
      #pragma unroll
      for (int j = 0; j < 4; ++j)
        acc[i][j] = mfma_bf16(af[i], bfr[j], acc[i][j]);
    __syncthreads();
    roff ^= 24576u;
  }

  int rbase = wm * 64 + ((lane >> 4) << 2);
  int cbase = n0 + wn * 64 + (lane & 15);
  #pragma unroll
  for (int i = 0; i < 4; ++i) {
    #pragma unroll
    for (int q = 0; q < 4; ++q) {
      int mg = m0 + rbase + i * 16 + q;
      if (mg < cnt) {
        size_t yrow = (size_t)(offe + mg) * DM;
        #pragma unroll
        for (int j = 0; j < 4; ++j) {
          int col = cbase + j * 16;
          Y[yrow + col] = (bf16_t)(acc[i][j][q] + b2[e * DM + col]);
        }
      }
    }
  }
}

// ===== combine: out[t] += g0*Y[s0] + g1*Y[s1] (one wave per token, bf16 Y) =====
__global__ __launch_bounds__(256) void k_combine(
    const bf16_t* __restrict__ Y, const int* __restrict__ t2s,
    const float* __restrict__ gl, float* __restrict__ out)
{
  int lane = threadIdx.x & 63, wv = threadIdx.x >> 6;
  int t = blockIdx.x * 4 + wv;
  int s0 = t2s[t*2], s1 = t2s[t*2 + 1];
  float g0 = gl[s0], g1 = gl[s1];
  const bf16_t* y0 = Y + (size_t)s0 * DM;
  const bf16_t* y1 = Y + (size_t)s1 * DM;
  float* o = out + (size_t)t * DM;
  #pragma unroll
  for (int c = 0; c < 4; ++c) {
    int d = c * 256 + lane * 4;
    float4 r  = *(const float4*)(o + d);
    bf16x4 a = *(const bf16x4*)(y0 + d);
    bf16x4 b = *(const bf16x4*)(y1 + d);
    r.x += g0 * (float)a[0] + g1 * (float)b[0];
    r.y += g0 * (float)a[1] + g1 * (float)b[1];
    r.z += g0 * (float)a[2] + g1 * (float)b[2];
    r.w += g0 * (float)a[3] + g1 * (float)b[3];
    *(float4*)(o + d) = r;
  }
}

// ============================ launch ============================
extern "C" void kernel_launch(void* const* d_in, const int* in_sizes, int n_in,
                              void* d_out, int out_size, void* d_ws, size_t ws_size,
                              hipStream_t stream) {
  const float* x      = (const float*)d_in[0];
  const float* gate_w = (const float*)d_in[1];
  const float* ln_g   = (const float*)d_in[2];
  const float* ln_b   = (const float*)d_in[3];
  const float* w1     = (const float*)d_in[4];
  const float* b1     = (const float*)d_in[5];
  const float* w2     = (const float*)d_in[6];
  const float* b2     = (const float*)d_in[7];
  float* out = (float*)d_out;

  char* ws = (char*)d_ws;
  bf16_t* xn   = (bf16_t*)(ws);                                  // 16 MiB
  bf16_t* w1t  = (bf16_t*)(ws + 16777216ull);                    // 64 MiB [E][F][D]; dead after ffn1
  bf16_t* Y    = (bf16_t*)(ws + 16777216ull);                    //   reused: Y [NP][DM] bf16 (32 MiB)
  bf16_t* w2t  = (bf16_t*)(ws + 83886080ull);                    // 64 MiB [E][D][F]
  bf16_t* H    = (bf16_t*)(ws + 150994944ull);                   // 128 MiB [NP][F]
  int*    list = (int*)   (ws + 285212672ull);
  float*  gl   = (float*) (ws + 285278208ull);
  int*    eidx = (int*)   (ws + 285343744ull);
  float*  gts  = (float*) (ws + 285409280ull);                   // aliased as t2s after k_assign
  int*    t2s  = (int*)   (ws + 285409280ull);
  int*    meta = (int*)   (ws + 285474816ull);

  hipMemsetAsync(meta, 0, 256, stream);
  k_router<<<T_TOK / 4, 256, 0, stream>>>(x, gate_w, ln_g, ln_b, out, xn, eidx, gts, meta);
  k_convT<<<dim3(DF / 64, DM / 64, NE), 256, 0, stream>>>(w1, w1t, DM, DF);
  k_convT<<<dim3(DM / 64, DF / 64, NE), 256, 0, stream>>>(w2, w2t, DF, DM);
  k_finalize<<<1, 1, 0, stream>>>(meta, out + (size_t)T_TOK * DM);
  k_assign<<<T_TOK / 256, 256, 0, stream>>>(eidx, gts, meta, list, gl, t2s);
  k_ffn1<<<dim3(DF / 128, 64, NE), 256, 0, stream>>>(xn, w1t, b1, H, list, meta);
  k_ffn2<<<dim3(DM / 256, 64, NE), 512, 0, stream>>>(H, w2t, b2, Y, meta);
  k_combine<<<T_TOK / 4, 256, 0, stream>>>(Y, t2s, gl, out);
}

// Round 7
// 686.753 us; speedup vs baseline: 1.3254x; 1.0244x over previous
//
#include <hip/hip_runtime.h>
#include <math.h>

typedef __bf16 bf16_t;
typedef bf16_t bf16x8 __attribute__((ext_vector_type(8)));
typedef bf16_t bf16x4 __attribute__((ext_vector_type(4)));
typedef float  f32x4  __attribute__((ext_vector_type(4)));

#define T_TOK 8192
#define DM 1024
#define DF 4096
#define NE 8
#define NP 16384  // total token-expert pairs = T_TOK * 2

__device__ __forceinline__ f32x4 mfma_bf16(bf16x8 a, bf16x8 b, f32x4 c) {
  return __builtin_amdgcn_mfma_f32_16x16x32_bf16(a, b, c, 0, 0, 0);
}

__device__ __forceinline__ void gload16(const void* g, void* l) {
  __builtin_amdgcn_global_load_lds((const __attribute__((address_space(1))) void*)g,
                                   (__attribute__((address_space(3))) void*)l, 16, 0, 0);
}

// Abramowitz-Stegun 7.1.26 erf, |err| <= 1.5e-7
__device__ __forceinline__ float erf_fast(float x) {
  float ax = fabsf(x);
  float t = 1.f / (1.f + 0.3275911f * ax);
  float p = t * (0.254829592f + t * (-0.284496736f + t * (1.421413741f +
            t * (-1.453152027f + t * 1.061405429f))));
  float r = 1.f - p * __expf(-ax * ax);
  return copysignf(r, x);
}

// Line-pair LDS swizzle (zero-conflict at BK=32, 64B rows):
// byte(row,ch) = (row>>1)*128 + ((((row&1)<<2)|ch) ^ ((row>>1)&7))*16
// Stage inverse for linear slot s: line=s>>3, u=s&7, w=u^(line&7), row=2*line+(w>>2), ch=w&3.
__device__ __forceinline__ unsigned swz_off(int row, int ch) {
  return (unsigned)(((row >> 1) << 7) + (((((row & 1) << 2) | ch) ^ ((row >> 1) & 7)) << 4));
}

// meta layout (ints): [0..7]=cnt1 [8..15]=cnt2 [16..23]=cursor [24..31]=off
// [32..39]=probsum(float) [40]=zsum(float)

// ============================ router ============================
__global__ __launch_bounds__(256) void k_router(
    const float* __restrict__ x, const float* __restrict__ gate_w,
    const float* __restrict__ ln_g, const float* __restrict__ ln_b,
    float* __restrict__ out, bf16_t* __restrict__ xn,
    int* __restrict__ eidx, float* __restrict__ gts, int* __restrict__ meta)
{
  int* cnt1 = meta;
  int* cnt2 = meta + 8;
  float* probsum = (float*)(meta + 32);
  float* zsum    = (float*)(meta + 40);

  __shared__ float sprob[8];
  __shared__ float sz;
  __shared__ int sc1[8], sc2[8];
  if (threadIdx.x < 8) { sprob[threadIdx.x] = 0.f; sc1[threadIdx.x] = 0; sc2[threadIdx.x] = 0; }
  if (threadIdx.x == 8) sz = 0.f;
  __syncthreads();

  int lane = threadIdx.x & 63, wv = threadIdx.x >> 6;
  int t = blockIdx.x * 4 + wv;
  const float* xt = x + (size_t)t * DM;

  float4 v[4];
  float s1 = 0.f, s2 = 0.f;
  #pragma unroll
  for (int c = 0; c < 4; ++c) {
    v[c] = *(const float4*)(xt + c * 256 + lane * 4);
    s1 += v[c].x + v[c].y + v[c].z + v[c].w;
    s2 += v[c].x * v[c].x + v[c].y * v[c].y + v[c].z * v[c].z + v[c].w * v[c].w;
  }
  #pragma unroll
  for (int o = 32; o > 0; o >>= 1) { s1 += __shfl_xor(s1, o, 64); s2 += __shfl_xor(s2, o, 64); }
  float mu = s1 * (1.f / DM);
  float var = s2 * (1.f / DM) - mu * mu;
  float rstd = rsqrtf(var + 1e-5f);

  float xv[16];
  #pragma unroll
  for (int c = 0; c < 4; ++c) {
    int d = c * 256 + lane * 4;
    float4 g4 = *(const float4*)(ln_g + d);
    float4 b4 = *(const float4*)(ln_b + d);
    xv[c*4+0] = (v[c].x - mu) * rstd * g4.x + b4.x;
    xv[c*4+1] = (v[c].y - mu) * rstd * g4.y + b4.y;
    xv[c*4+2] = (v[c].z - mu) * rstd * g4.z + b4.z;
    xv[c*4+3] = (v[c].w - mu) * rstd * g4.w + b4.w;
    *(float4*)(out + (size_t)t * DM + d) = v[c];  // residual init
    bf16x4 pk = { (bf16_t)xv[c*4+0], (bf16_t)xv[c*4+1], (bf16_t)xv[c*4+2], (bf16_t)xv[c*4+3] };
    *(bf16x4*)(xn + (size_t)t * DM + d) = pk;
  }

  float lg[8];
  #pragma unroll
  for (int e = 0; e < 8; ++e) {
    float p = 0.f;
    #pragma unroll
    for (int c = 0; c < 4; ++c) {
      int d = c * 256 + lane * 4;
      float4 g4 = *(const float4*)(gate_w + e * DM + d);
      p += xv[c*4+0] * g4.x + xv[c*4+1] * g4.y + xv[c*4+2] * g4.z + xv[c*4+3] * g4.w;
    }
    #pragma unroll
    for (int o = 32; o > 0; o >>= 1) p += __shfl_xor(p, o, 64);
    lg[e] = p;
  }

  if (lane == 0) {
    float m = -1e30f;
    #pragma unroll
    for (int e = 0; e < 8; ++e) { lg[e] = fminf(fmaxf(lg[e], -10.f), 10.f); m = fmaxf(m, lg[e]); }
    float pr[8]; float se = 0.f;
    #pragma unroll
    for (int e = 0; e < 8; ++e) { pr[e] = expf(lg[e] - m); se += pr[e]; }
    float inv = 1.f / se;
    #pragma unroll
    for (int e = 0; e < 8; ++e) pr[e] *= inv;
    float lse = m + logf(se);

    int e0 = 0; float p0 = pr[0];
    #pragma unroll
    for (int e = 1; e < 8; ++e) if (pr[e] > p0) { p0 = pr[e]; e0 = e; }
    int e1 = -1; float p1 = -1.f;
    #pragma unroll
    for (int e = 0; e < 8; ++e) if (e != e0 && pr[e] > p1) { p1 = pr[e]; e1 = e; }
    float s = p0 + p1 + 1e-8f;
    eidx[t*2]   = e0; eidx[t*2+1] = e1;
    gts[t*2]    = p0 / s; gts[t*2+1] = p1 / s;

    atomicAdd(&sc1[e0], 1);
    atomicAdd(&sc2[e0], 1);
    atomicAdd(&sc2[e1], 1);
    #pragma unroll
    for (int e = 0; e < 8; ++e) atomicAdd(&sprob[e], pr[e]);
    atomicAdd(&sz, lse * lse);
  }
  __syncthreads();
  if (threadIdx.x < 8) {
    if (sc1[threadIdx.x]) atomicAdd(&cnt1[threadIdx.x], sc1[threadIdx.x]);
    if (sc2[threadIdx.x]) atomicAdd(&cnt2[threadIdx.x], sc2[threadIdx.x]);
    atomicAdd(&probsum[threadIdx.x], sprob[threadIdx.x]);
  }
  if (threadIdx.x == 8) atomicAdd(zsum, sz);
}

// ========== weight convert + transpose: src [R][C] fp32 -> dst [C][R] bf16 ==========
__global__ __launch_bounds__(256) void k_convT(
    const float* __restrict__ src, bf16_t* __restrict__ dst, int R, int C)
{
  __shared__ float tile[64][65];
  int e = blockIdx.z;
  const float* s = src + (size_t)e * R * C;
  bf16_t* d = dst + (size_t)e * R * C;
  int c0 = blockIdx.x * 64, r0 = blockIdx.y * 64;
  int t = threadIdx.x;
  #pragma unroll
  for (int i = 0; i < 4; ++i) {
    int idx = i * 256 + t;
    int r = idx >> 4, c4 = (idx & 15) * 4;
    float4 v = *(const float4*)(s + (size_t)(r0 + r) * C + c0 + c4);
    tile[r][c4]   = v.x; tile[r][c4+1] = v.y;
    tile[r][c4+2] = v.z; tile[r][c4+3] = v.w;
  }
  __syncthreads();
  #pragma unroll
  for (int i = 0; i < 2; ++i) {
    int idx = i * 256 + t;
    int c = idx >> 3, r8 = (idx & 7) * 8;
    bf16x8 pk;
    #pragma unroll
    for (int k = 0; k < 8; ++k) pk[k] = (bf16_t)tile[r8 + k][c];
    *(bf16x8*)(d + (size_t)(c0 + c) * R + r0 + r8) = pk;
  }
}

// ============================ tiny serial kernels ============================
__global__ void k_finalize(int* __restrict__ meta, float* __restrict__ aux_out) {
  if (threadIdx.x == 0 && blockIdx.x == 0) {
    int acc = 0;
    for (int e = 0; e < 8; ++e) { meta[24 + e] = acc; acc += meta[8 + e]; }
    const float* probsum = (const float*)(meta + 32);
    const float* zsum    = (const float*)(meta + 40);
    float s = 0.f;
    for (int e = 0; e < 8; ++e)
      s += ((float)meta[e] * (1.f / 8192.f)) * (probsum[e] * (1.f / 8192.f));
    aux_out[0] = 8.f * s * 0.01f + (zsum[0] * (1.f / 8192.f)) * 0.001f;
  }
}

__global__ __launch_bounds__(256) void k_assign(
    const int* __restrict__ eidx, float* __restrict__ gts,
    int* __restrict__ meta, int* __restrict__ list, float* __restrict__ gl,
    int* __restrict__ t2s)
{
  int t = blockIdx.x * 256 + threadIdx.x;
  int* cursor = meta + 16;
  const int* off = meta + 24;
  #pragma unroll
  for (int k = 0; k < 2; ++k) {
    int e = eidx[t*2 + k];
    float g = gts[t*2 + k];          // read before aliased write
    int pos = atomicAdd(&cursor[e], 1);
    int slot = off[e] + pos;
    list[slot] = t;
    gl[slot] = g;
    t2s[t*2 + k] = slot;
  }
}

// ===== GEMM geometry: 128x256 block, BK=32, 4 waves, per-wave 128x64 output =====
// LDS dbuf: buf0 @0, buf1 @24576; within buf: A[128][32] (8KB) @0, B[256][32] (16KB) @8192.
// Line-pair swizzle (zero bank conflicts): see swz_off. Staged via pre-swizzled per-lane
// global source + linear gload_lds dest (rule #21 both-sides). Loop unrolled x2 so buffer
// offsets are literals; one __syncthreads per K-tile (drains prefetch after compute overlap).

#define STAGE1(KT, BO) do { \
  _Pragma("unroll") for (int r = 0; r < 2; ++r) gload16(sA[r] + (KT) * 32, smem + (BO) + dA[r]); \
  _Pragma("unroll") for (int r = 0; r < 4; ++r) gload16(sB[r] + (KT) * 32, smem + (BO) + dB[r]); \
} while (0)

#define COMPUTE1(BO) do { \
  bf16x8 bfr[4]; \
  _Pragma("unroll") for (int j = 0; j < 4; ++j) bfr[j] = *(const bf16x8*)(smem + (BO) + b_off[j]); \
  _Pragma("unroll") for (int i = 0; i < 8; ++i) { \
    bf16x8 af = *(const bf16x8*)(smem + (BO) + a_off[i]); \
    _Pragma("unroll") for (int j = 0; j < 4; ++j) acc[i][j] = mfma_bf16(af, bfr[j], acc[i][j]); \
  } \
} while (0)

// ============ GEMM1: H = gelu(Xn[list] @ W1t^T + b1), K=DM ============
__global__ __launch_bounds__(256, 2) void k_ffn1(
    const bf16_t* __restrict__ xn, const bf16_t* __restrict__ w1t,
    const float* __restrict__ b1, bf16_t* __restrict__ H,
    const int* __restrict__ list, const int* __restrict__ meta)
{
  int e = blockIdx.z;
  int cnt = meta[8 + e];
  int m0 = blockIdx.y * 128;
  if (m0 >= cnt) return;
  int offe = meta[24 + e];
  int n0 = blockIdx.x * 256;

  __shared__ __align__(1024) char smem[49152];
  int tid = threadIdx.x, lane = tid & 63, wv = tid >> 6;

  const bf16_t* sA[2]; const bf16_t* sB[4];
  unsigned dA[2], dB[4];
  #pragma unroll
  for (int i = 0; i < 2; ++i) {
    int s = i * 256 + tid;
    int line = s >> 3, u = s & 7, w = u ^ (line & 7);
    int row = (line << 1) | (w >> 2), ch = w & 3;
    int mrow = min(m0 + row, cnt - 1);
    int token = list[offe + mrow];
    sA[i] = xn + (size_t)token * DM + ch * 8;
    dA[i] = (unsigned)(i * 4096 + wv * 1024);
  }
  #pragma unroll
  for (int i = 0; i < 4; ++i) {
    int s = i * 256 + tid;
    int line = s >> 3, u = s & 7, w = u ^ (line & 7);
    int row = (line << 1) | (w >> 2), ch = w & 3;
    sB[i] = w1t + ((size_t)e * DF + n0 + row) * DM + ch * 8;
    dB[i] = (unsigned)(8192 + i * 4096 + wv * 1024);
  }

  unsigned a_off[8], b_off[4];
  #pragma unroll
  for (int i = 0; i < 8; ++i) a_off[i] = swz_off(i * 16 + (lane & 15), lane >> 4);
  #pragma unroll
  for (int j = 0; j < 4; ++j) b_off[j] = 8192u + swz_off(wv * 64 + j * 16 + (lane & 15), lane >> 4);

  f32x4 acc[8][4];
  #pragma unroll
  for (int i = 0; i < 8; ++i)
    #pragma unroll
    for (int j = 0; j < 4; ++j)
      acc[i][j] = (f32x4){0.f, 0.f, 0.f, 0.f};

  STAGE1(0, 0);
  __syncthreads();
  for (int kt = 0; kt < DM / 32; kt += 2) {
    STAGE1(kt + 1, 24576);
    COMPUTE1(0);
    __syncthreads();
    if (kt + 2 < DM / 32) STAGE1(kt + 2, 0);
    COMPUTE1(24576);
    __syncthreads();
  }

  int rq = (lane >> 4) << 2;
  int cbase = n0 + wv * 64 + (lane & 15);
  #pragma unroll
  for (int i = 0; i < 8; ++i) {
    #pragma unroll
    for (int q = 0; q < 4; ++q) {
      int mg = m0 + i * 16 + rq + q;
      if (mg < cnt) {
        size_t hrow = (size_t)(offe + mg) * DF;
        #pragma unroll
        for (int j = 0; j < 4; ++j) {
          int col = cbase + j * 16;
          float hv = acc[i][j][q] + b1[e * DF + col];
          hv = 0.5f * hv * (1.f + erf_fast(hv * 0.70710678118f));
          H[hrow + col] = (bf16_t)hv;
        }
      }
    }
  }
}

// ============ GEMM2: Y[slot] = H[slot] @ W2t^T + b2 (bf16, no atomics), K=DF ============
__global__ __launch_bounds__(256, 2) void k_ffn2(
    const bf16_t* __restrict__ H, const bf16_t* __restrict__ w2t,
    const float* __restrict__ b2, bf16_t* __restrict__ Y,
    const int* __restrict__ meta)
{
  int e = blockIdx.z;
  int cnt = meta[8 + e];
  int m0 = blockIdx.y * 128;
  if (m0 >= cnt) return;
  int offe = meta[24 + e];
  int n0 = blockIdx.x * 256;

  __shared__ __align__(1024) char smem[49152];
  int tid = threadIdx.x, lane = tid & 63, wv = tid >> 6;

  const bf16_t* sA[2]; const bf16_t* sB[4];
  unsigned dA[2], dB[4];
  #pragma unroll
  for (int i = 0; i < 2; ++i) {
    int s = i * 256 + tid;
    int line = s >> 3, u = s & 7, w = u ^ (line & 7);
    int row = (line << 1) | (w >> 2), ch = w & 3;
    int mrow = min(m0 + row, cnt - 1);
    sA[i] = H + (size_t)(offe + mrow) * DF + ch * 8;
    dA[i] = (unsigned)(i * 4096 + wv * 1024);
  }
  #pragma unroll
  for (int i = 0; i < 4; ++i) {
    int s = i * 256 + tid;
    int line = s >> 3, u = s & 7, w = u ^ (line & 7);
    int row = (line << 1) | (w >> 2), ch = w & 3;
    sB[i] = w2t + ((size_t)e * DM + n0 + row) * DF + ch * 8;
    dB[i] = (unsigned)(8192 + i * 4096 + wv * 1024);
  }

  unsigned a_off[8], b_off[4];
  #pragma unroll
  for (int i = 0; i < 8; ++i) a_off[i] = swz_off(i * 16 + (lane & 15), lane >> 4);
  #pragma unroll
  for (int j = 0; j < 4; ++j) b_off[j] = 8192u + swz_off(wv * 64 + j * 16 + (lane & 15), lane >> 4);

  f32x4 acc[8][4];
  #pragma unroll
  for (int i = 0; i < 8; ++i)
    #pragma unroll
    for (int j = 0; j < 4; ++j)
      acc[i][j] = (f32x4){0.f, 0.f, 0.f, 0.f};

  STAGE1(0, 0);
  __syncthreads();
  for (int kt = 0; kt < DF / 32; kt += 2) {
    STAGE1(kt + 1, 24576);
    COMPUTE1(0);
    __syncthreads();
    if (kt + 2 < DF / 32) STAGE1(kt + 2, 0);
    COMPUTE1(24576);
    __syncthreads();
  }

  int rq = (lane >> 4) << 2;
  int cbase = n0 + wv * 64 + (lane & 15);
  #pragma unroll
  for (int i = 0; i < 8; ++i) {
    #pragma unroll
    for (int q = 0; q < 4; ++q) {
      int mg = m0 + i * 16 + rq + q;
      if (mg < cnt) {
        size_t yrow = (size_t)(offe + mg) * DM;
        #pragma unroll
        for (int j = 0; j < 4; ++j) {
          int col = cbase + j * 16;
          Y[yrow + col] = (bf16_t)(acc[i][j][q] + b2[e * DM + col]);
        }
      }
    }
  }
}

// ===== combine: out[t] += g0*Y[s0] + g1*Y[s1] (one wave per token, bf16 Y) =====
__global__ __launch_bounds__(256) void k_combine(
    const bf16_t* __restrict__ Y, const int* __restrict__ t2s,
    const float* __restrict__ gl, float* __restrict__ out)
{
  int lane = threadIdx.x & 63, wv = threadIdx.x >> 6;
  int t = blockIdx.x * 4 + wv;
  int s0 = t2s[t*2], s1 = t2s[t*2 + 1];
  float g0 = gl[s0], g1 = gl[s1];
  const bf16_t* y0 = Y + (size_t)s0 * DM;
  const bf16_t* y1 = Y + (size_t)s1 * DM;
  float* o = out + (size_t)t * DM;
  #pragma unroll
  for (int c = 0; c < 4; ++c) {
    int d = c * 256 + lane * 4;
    float4 r  = *(const float4*)(o + d);
    bf16x4 a = *(const bf16x4*)(y0 + d);
    bf16x4 b = *(const bf16x4*)(y1 + d);
    r.x += g0 * (float)a[0] + g1 * (float)b[0];
    r.y += g0 * (float)a[1] + g1 * (float)b[1];
    r.z += g0 * (float)a[2] + g1 * (float)b[2];
    r.w += g0 * (float)a[3] + g1 * (float)b[3];
    *(float4*)(o + d) = r;
  }
}

// ============================ launch ============================
extern "C" void kernel_launch(void* const* d_in, const int* in_sizes, int n_in,
                              void* d_out, int out_size, void* d_ws, size_t ws_size,
                              hipStream_t stream) {
  const float* x      = (const float*)d_in[0];
  const float* gate_w = (const float*)d_in[1];
  const float* ln_g   = (const float*)d_in[2];
  const float* ln_b   = (const float*)d_in[3];
  const float* w1     = (const float*)d_in[4];
  const float* b1     = (const float*)d_in[5];
  const float* w2     = (const float*)d_in[6];
  const float* b2     = (const float*)d_in[7];
  float* out = (float*)d_out;

  char* ws = (char*)d_ws;
  bf16_t* xn   = (bf16_t*)(ws);                                  // 16 MiB
  bf16_t* w1t  = (bf16_t*)(ws + 16777216ull);                    // 64 MiB [E][F][D]; dead after ffn1
  bf16_t* Y    = (bf16_t*)(ws + 16777216ull);                    //   reused: Y [NP][DM] bf16 (32 MiB)
  bf16_t* w2t  = (bf16_t*)(ws + 83886080ull);                    // 64 MiB [E][D][F]
  bf16_t* H    = (bf16_t*)(ws + 150994944ull);                   // 128 MiB [NP][F]
  int*    list = (int*)   (ws + 285212672ull);
  float*  gl   = (float*) (ws + 285278208ull);
  int*    eidx = (int*)   (ws + 285343744ull);
  float*  gts  = (float*) (ws + 285409280ull);                   // aliased as t2s after k_assign
  int*    t2s  = (int*)   (ws + 285409280ull);
  int*    meta = (int*)   (ws + 285474816ull);

  hipMemsetAsync(meta, 0, 256, stream);
  k_router<<<T_TOK / 4, 256, 0, stream>>>(x, gate_w, ln_g, ln_b, out, xn, eidx, gts, meta);
  k_convT<<<dim3(DF / 64, DM / 64, NE), 256, 0, stream>>>(w1, w1t, DM, DF);
  k_convT<<<dim3(DM / 64, DF / 64, NE), 256, 0, stream>>>(w2, w2t, DF, DM);
  k_finalize<<<1, 1, 0, stream>>>(meta, out + (size_t)T_TOK * DM);
  k_assign<<<T_TOK / 256, 256, 0, stream>>>(eidx, gts, meta, list, gl, t2s);
  k_ffn1<<<dim3(DF / 256, 64, NE), 256, 0, stream>>>(xn, w1t, b1, H, list, meta);
  k_ffn2<<<dim3(DM / 256, 64, NE), 256, 0, stream>>>(H, w2t, b2, Y, meta);
  k_combine<<<T_TOK / 4, 256, 0, stream>>>(Y, t2s, gl, out);
}

// Round 8
// 685.527 us; speedup vs baseline: 1.3278x; 1.0018x over previous
//
#include <hip/hip_runtime.h>
#include <math.h>

typedef __bf16 bf16_t;
typedef bf16_t bf16x8 __attribute__((ext_vector_type(8)));
typedef bf16_t bf16x4 __attribute__((ext_vector_type(4)));
typedef float  f32x4  __attribute__((ext_vector_type(4)));

#define T_TOK 8192
#define DM 1024
#define DF 4096
#define NE 8
#define NP 16384  // total token-expert pairs = T_TOK * 2

__device__ __forceinline__ f32x4 mfma_bf16(bf16x8 a, bf16x8 b, f32x4 c) {
  return __builtin_amdgcn_mfma_f32_16x16x32_bf16(a, b, c, 0, 0, 0);
}

__device__ __forceinline__ void gload16(const void* g, void* l) {
  __builtin_amdgcn_global_load_lds((const __attribute__((address_space(1))) void*)g,
                                   (__attribute__((address_space(3))) void*)l, 16, 0, 0);
}

// Abramowitz-Stegun 7.1.26 erf, |err| <= 1.5e-7
__device__ __forceinline__ float erf_fast(float x) {
  float ax = fabsf(x);
  float t = 1.f / (1.f + 0.3275911f * ax);
  float p = t * (0.254829592f + t * (-0.284496736f + t * (1.421413741f +
            t * (-1.453152027f + t * 1.061405429f))));
  float r = 1.f - p * __expf(-ax * ax);
  return copysignf(r, x);
}

// Line-pair LDS swizzle (zero-conflict at BK=32, 64B rows):
// byte(row,ch) = (row>>1)*128 + ((((row&1)<<2)|ch) ^ ((row>>1)&7))*16
// Stage inverse for linear slot s: line=s>>3, u=s&7, w=u^(line&7), row=2*line+(w>>2), ch=w&3.
__device__ __forceinline__ unsigned swz_off(int row, int ch) {
  return (unsigned)(((row >> 1) << 7) + (((((row & 1) << 2) | ch) ^ ((row >> 1) & 7)) << 4));
}

// meta layout (ints): [0..7]=cnt1 [8..15]=cnt2 [16..23]=cursor [24..31]=off
// [32..39]=probsum(float) [40]=zsum(float)

// ============================ router ============================
__global__ __launch_bounds__(256) void k_router(
    const float* __restrict__ x, const float* __restrict__ gate_w,
    const float* __restrict__ ln_g, const float* __restrict__ ln_b,
    float* __restrict__ out, bf16_t* __restrict__ xn,
    int* __restrict__ eidx, float* __restrict__ gts, int* __restrict__ meta)
{
  int* cnt1 = meta;
  int* cnt2 = meta + 8;
  float* probsum = (float*)(meta + 32);
  float* zsum    = (float*)(meta + 40);

  __shared__ float sprob[8];
  __shared__ float sz;
  __shared__ int sc1[8], sc2[8];
  if (threadIdx.x < 8) { sprob[threadIdx.x] = 0.f; sc1[threadIdx.x] = 0; sc2[threadIdx.x] = 0; }
  if (threadIdx.x == 8) sz = 0.f;
  __syncthreads();

  int lane = threadIdx.x & 63, wv = threadIdx.x >> 6;
  int t = blockIdx.x * 4 + wv;
  const float* xt = x + (size_t)t * DM;

  float4 v[4];
  float s1 = 0.f, s2 = 0.f;
  #pragma unroll
  for (int c = 0; c < 4; ++c) {
    v[c] = *(const float4*)(xt + c * 256 + lane * 4);
    s1 += v[c].x + v[c].y + v[c].z + v[c].w;
    s2 += v[c].x * v[c].x + v[c].y * v[c].y + v[c].z * v[c].z + v[c].w * v[c].w;
  }
  #pragma unroll
  for (int o = 32; o > 0; o >>= 1) { s1 += __shfl_xor(s1, o, 64); s2 += __shfl_xor(s2, o, 64); }
  float mu = s1 * (1.f / DM);
  float var = s2 * (1.f / DM) - mu * mu;
  float rstd = rsqrtf(var + 1e-5f);

  float xv[16];
  #pragma unroll
  for (int c = 0; c < 4; ++c) {
    int d = c * 256 + lane * 4;
    float4 g4 = *(const float4*)(ln_g + d);
    float4 b4 = *(const float4*)(ln_b + d);
    xv[c*4+0] = (v[c].x - mu) * rstd * g4.x + b4.x;
    xv[c*4+1] = (v[c].y - mu) * rstd * g4.y + b4.y;
    xv[c*4+2] = (v[c].z - mu) * rstd * g4.z + b4.z;
    xv[c*4+3] = (v[c].w - mu) * rstd * g4.w + b4.w;
    *(float4*)(out + (size_t)t * DM + d) = v[c];  // residual init
    bf16x4 pk = { (bf16_t)xv[c*4+0], (bf16_t)xv[c*4+1], (bf16_t)xv[c*4+2], (bf16_t)xv[c*4+3] };
    *(bf16x4*)(xn + (size_t)t * DM + d) = pk;
  }

  float lg[8];
  #pragma unroll
  for (int e = 0; e < 8; ++e) {
    float p = 0.f;
    #pragma unroll
    for (int c = 0; c < 4; ++c) {
      int d = c * 256 + lane * 4;
      float4 g4 = *(const float4*)(gate_w + e * DM + d);
      p += xv[c*4+0] * g4.x + xv[c*4+1] * g4.y + xv[c*4+2] * g4.z + xv[c*4+3] * g4.w;
    }
    #pragma unroll
    for (int o = 32; o > 0; o >>= 1) p += __shfl_xor(p, o, 64);
    lg[e] = p;
  }

  if (lane == 0) {
    float m = -1e30f;
    #pragma unroll
    for (int e = 0; e < 8; ++e) { lg[e] = fminf(fmaxf(lg[e], -10.f), 10.f); m = fmaxf(m, lg[e]); }
    float pr[8]; float se = 0.f;
    #pragma unroll
    for (int e = 0; e < 8; ++e) { pr[e] = expf(lg[e] - m); se += pr[e]; }
    float inv = 1.f / se;
    #pragma unroll
    for (int e = 0; e < 8; ++e) pr[e] *= inv;
    float lse = m + logf(se);

    int e0 = 0; float p0 = pr[0];
    #pragma unroll
    for (int e = 1; e < 8; ++e) if (pr[e] > p0) { p0 = pr[e]; e0 = e; }
    int e1 = -1; float p1 = -1.f;
    #pragma unroll
    for (int e = 0; e < 8; ++e) if (e != e0 && pr[e] > p1) { p1 = pr[e]; e1 = e; }
    float s = p0 + p1 + 1e-8f;
    eidx[t*2]   = e0; eidx[t*2+1] = e1;
    gts[t*2]    = p0 / s; gts[t*2+1] = p1 / s;

    atomicAdd(&sc1[e0], 1);
    atomicAdd(&sc2[e0], 1);
    atomicAdd(&sc2[e1], 1);
    #pragma unroll
    for (int e = 0; e < 8; ++e) atomicAdd(&sprob[e], pr[e]);
    atomicAdd(&sz, lse * lse);
  }
  __syncthreads();
  if (threadIdx.x < 8) {
    if (sc1[threadIdx.x]) atomicAdd(&cnt1[threadIdx.x], sc1[threadIdx.x]);
    if (sc2[threadIdx.x]) atomicAdd(&cnt2[threadIdx.x], sc2[threadIdx.x]);
    atomicAdd(&probsum[threadIdx.x], sprob[threadIdx.x]);
  }
  if (threadIdx.x == 8) atomicAdd(zsum, sz);
}

// ========== merged weight convert+transpose (w1 and w2 in one grid) ==========
// job < 8192: w1 [DM][DF] -> w1t [DF][DM];  job >= 8192: w2 [DF][DM] -> w2t [DM][DF]
__global__ __launch_bounds__(256) void k_convT2(
    const float* __restrict__ w1, bf16_t* __restrict__ w1t,
    const float* __restrict__ w2, bf16_t* __restrict__ w2t)
{
  int bid = blockIdx.x;
  const float* s; bf16_t* d; int R, C, c0, r0;
  if (bid < 8192) {
    int e = bid >> 10, rem = bid & 1023;
    R = DM; C = DF;
    s = w1 + (size_t)e * R * C; d = w1t + (size_t)e * R * C;
    c0 = (rem & 63) * 64; r0 = (rem >> 6) * 64;
  } else {
    int e = (bid - 8192) >> 10, rem = (bid - 8192) & 1023;
    R = DF; C = DM;
    s = w2 + (size_t)e * R * C; d = w2t + (size_t)e * R * C;
    c0 = (rem & 15) * 64; r0 = (rem >> 4) * 64;
  }

  __shared__ float tile[64][65];
  int t = threadIdx.x;
  #pragma unroll
  for (int i = 0; i < 4; ++i) {
    int idx = i * 256 + t;
    int r = idx >> 4, c4 = (idx & 15) * 4;
    float4 v = *(const float4*)(s + (size_t)(r0 + r) * C + c0 + c4);
    tile[r][c4]   = v.x; tile[r][c4+1] = v.y;
    tile[r][c4+2] = v.z; tile[r][c4+3] = v.w;
  }
  __syncthreads();
  #pragma unroll
  for (int i = 0; i < 2; ++i) {
    int idx = i * 256 + t;
    int c = idx >> 3, r8 = (idx & 7) * 8;
    bf16x8 pk;
    #pragma unroll
    for (int k = 0; k < 8; ++k) pk[k] = (bf16_t)tile[r8 + k][c];
    *(bf16x8*)(d + (size_t)(c0 + c) * R + r0 + r8) = pk;
  }
}

// ============================ tiny serial kernels ============================
__global__ void k_finalize(int* __restrict__ meta, float* __restrict__ aux_out) {
  if (threadIdx.x == 0 && blockIdx.x == 0) {
    int acc = 0;
    for (int e = 0; e < 8; ++e) { meta[24 + e] = acc; acc += meta[8 + e]; }
    const float* probsum = (const float*)(meta + 32);
    const float* zsum    = (const float*)(meta + 40);
    float s = 0.f;
    for (int e = 0; e < 8; ++e)
      s += ((float)meta[e] * (1.f / 8192.f)) * (probsum[e] * (1.f / 8192.f));
    aux_out[0] = 8.f * s * 0.01f + (zsum[0] * (1.f / 8192.f)) * 0.001f;
  }
}

__global__ __launch_bounds__(256) void k_assign(
    const int* __restrict__ eidx, float* __restrict__ gts,
    int* __restrict__ meta, int* __restrict__ list, float* __restrict__ gl,
    int* __restrict__ t2s)
{
  int t = blockIdx.x * 256 + threadIdx.x;
  int* cursor = meta + 16;
  const int* off = meta + 24;
  #pragma unroll
  for (int k = 0; k < 2; ++k) {
    int e = eidx[t*2 + k];
    float g = gts[t*2 + k];          // read before aliased write
    int pos = atomicAdd(&cursor[e], 1);
    int slot = off[e] + pos;
    list[slot] = t;
    gl[slot] = g;
    t2s[t*2 + k] = slot;
  }
}

// ===== GEMM geometry: 128x256 block, BK=32, 4 waves, per-wave 128x64 output =====
// LDS dbuf: buf0 @0, buf1 @24576; within buf: A[128][32] (8KB) @0, B[256][32] (16KB) @8192.
// Line-pair swizzle (zero bank conflicts, R7-verified). Pre-swizzled global source +
// linear gload_lds dest (rule #21 both-sides).
//
// K-loop (counted-vmcnt pipeline, T4): per K-tile t:
//   STAGE(t+1 -> other buf)            (6 gload_lds/thread in flight)
//   s_waitcnt vmcnt(6)                 (tile t's 6 landed; t+1's 6 still flying)
//   s_barrier                          (all waves see tile t in LDS)
//   setprio(1); 32 MFMA + 12 ds_read; setprio(0)
//   s_barrier                          (all waves done reading this buf -> next STAGE may overwrite)
// vmcnt(0) only at the last tile. Hazards: RAW = own vmcnt + barrier; WAR = stage issued
// only after the barrier ending the target buffer's readers (ds_reads consumed by MFMA
// before that barrier). sched_barrier(0) pins ordering around the asm waitcnts.

#define STAGE1(KT, BO) do { \
  _Pragma("unroll") for (int r = 0; r < 2; ++r) gload16(sA[r] + (KT) * 32, smem + (BO) + dA[r]); \
  _Pragma("unroll") for (int r = 0; r < 4; ++r) gload16(sB[r] + (KT) * 32, smem + (BO) + dB[r]); \
} while (0)

#define COMPUTE1(BO) do { \
  bf16x8 bfr[4]; \
  _Pragma("unroll") for (int j = 0; j < 4; ++j) bfr[j] = *(const bf16x8*)(smem + (BO) + b_off[j]); \
  _Pragma("unroll") for (int i = 0; i < 8; ++i) { \
    bf16x8 af = *(const bf16x8*)(smem + (BO) + a_off[i]); \
    _Pragma("unroll") for (int j = 0; j < 4; ++j) acc[i][j] = mfma_bf16(af, bfr[j], acc[i][j]); \
  } \
} while (0)

#define WAITV6 do { __builtin_amdgcn_sched_barrier(0); \
  asm volatile("s_waitcnt vmcnt(6)" ::: "memory"); \
  __builtin_amdgcn_sched_barrier(0); __builtin_amdgcn_s_barrier(); \
  __builtin_amdgcn_sched_barrier(0); } while (0)

#define WAITV0 do { __builtin_amdgcn_sched_barrier(0); \
  asm volatile("s_waitcnt vmcnt(0)" ::: "memory"); \
  __builtin_amdgcn_sched_barrier(0); __builtin_amdgcn_s_barrier(); \
  __builtin_amdgcn_sched_barrier(0); } while (0)

#define ENDBAR do { __builtin_amdgcn_sched_barrier(0); \
  __builtin_amdgcn_s_barrier(); __builtin_amdgcn_sched_barrier(0); } while (0)

#define KLOOP(NT) do { \
  STAGE1(0, 0); \
  for (int kt = 0; kt < (NT); kt += 2) { \
    STAGE1(kt + 1, 24576); \
    WAITV6; \
    __builtin_amdgcn_s_setprio(1); \
    COMPUTE1(0); \
    __builtin_amdgcn_s_setprio(0); \
    ENDBAR; \
    if (kt + 2 < (NT)) { STAGE1(kt + 2, 0); WAITV6; } else { WAITV0; } \
    __builtin_amdgcn_s_setprio(1); \
    COMPUTE1(24576); \
    __builtin_amdgcn_s_setprio(0); \
    ENDBAR; \
  } \
} while (0)

// ============ GEMM1: H = gelu(Xn[list] @ W1t^T + b1), K=DM ============
__global__ __launch_bounds__(256, 2) void k_ffn1(
    const bf16_t* __restrict__ xn, const bf16_t* __restrict__ w1t,
    const float* __restrict__ b1, bf16_t* __restrict__ H,
    const int* __restrict__ list, const int* __restrict__ meta)
{
  int e = blockIdx.z;
  int cnt = meta[8 + e];
  int m0 = blockIdx.y * 128;
  if (m0 >= cnt) return;
  int offe = meta[24 + e];
  int n0 = blockIdx.x * 256;

  __shared__ __align__(1024) char smem[49152];
  int tid = threadIdx.x, lane = tid & 63, wv = tid >> 6;

  const bf16_t* sA[2]; const bf16_t* sB[4];
  unsigned dA[2], dB[4];
  #pragma unroll
  for (int i = 0; i < 2; ++i) {
    int s = i * 256 + tid;
    int line = s >> 3, u = s & 7, w = u ^ (line & 7);
    int row = (line << 1) | (w >> 2), ch = w & 3;
    int mrow = min(m0 + row, cnt - 1);
    int token = list[offe + mrow];
    sA[i] = xn + (size_t)token * DM + ch * 8;
    dA[i] = (unsigned)(i * 4096 + wv * 1024);
  }
  #pragma unroll
  for (int i = 0; i < 4; ++i) {
    int s = i * 256 + tid;
    int line = s >> 3, u = s & 7, w = u ^ (line & 7);
    int row = (line << 1) | (w >> 2), ch = w & 3;
    sB[i] = w1t + ((size_t)e * DF + n0 + row) * DM + ch * 8;
    dB[i] = (unsigned)(8192 + i * 4096 + wv * 1024);
  }

  unsigned a_off[8], b_off[4];
  #pragma unroll
  for (int i = 0; i < 8; ++i) a_off[i] = swz_off(i * 16 + (lane & 15), lane >> 4);
  #pragma unroll
  for (int j = 0; j < 4; ++j) b_off[j] = 8192u + swz_off(wv * 64 + j * 16 + (lane & 15), lane >> 4);

  f32x4 acc[8][4];
  #pragma unroll
  for (int i = 0; i < 8; ++i)
    #pragma unroll
    for (int j = 0; j < 4; ++j)
      acc[i][j] = (f32x4){0.f, 0.f, 0.f, 0.f};

  KLOOP(DM / 32);

  int rq = (lane >> 4) << 2;
  int cbase = n0 + wv * 64 + (lane & 15);
  #pragma unroll
  for (int i = 0; i < 8; ++i) {
    #pragma unroll
    for (int q = 0; q < 4; ++q) {
      int mg = m0 + i * 16 + rq + q;
      if (mg < cnt) {
        size_t hrow = (size_t)(offe + mg) * DF;
        #pragma unroll
        for (int j = 0; j < 4; ++j) {
          int col = cbase + j * 16;
          float hv = acc[i][j][q] + b1[e * DF + col];
          hv = 0.5f * hv * (1.f + erf_fast(hv * 0.70710678118f));
          H[hrow + col] = (bf16_t)hv;
        }
      }
    }
  }
}

// ============ GEMM2: Y[slot] = H[slot] @ W2t^T + b2 (bf16, no atomics), K=DF ============
__global__ __launch_bounds__(256, 2) void k_ffn2(
    const bf16_t* __restrict__ H, const bf16_t* __restrict__ w2t,
    const float* __restrict__ b2, bf16_t* __restrict__ Y,
    const int* __restrict__ meta)
{
  int e = blockIdx.z;
  int cnt = meta[8 + e];
  int m0 = blockIdx.y * 128;
  if (m0 >= cnt) return;
  int offe = meta[24 + e];
  int n0 = blockIdx.x * 256;

  __shared__ __align__(1024) char smem[49152];
  int tid = threadIdx.x, lane = tid & 63, wv = tid >> 6;

  const bf16_t* sA[2]; const bf16_t* sB[4];
  unsigned dA[2], dB[4];
  #pragma unroll
  for (int i = 0; i < 2; ++i) {
    int s = i * 256 + tid;
    int line = s >> 3, u = s & 7, w = u ^ (line & 7);
    int row = (line << 1) | (w >> 2), ch = w & 3;
    int mrow = min(m0 + row, cnt - 1);
    sA[i] = H + (size_t)(offe + mrow) * DF + ch * 8;
    dA[i] = (unsigned)(i * 4096 + wv * 1024);
  }
  #pragma unroll
  for (int i = 0; i < 4; ++i) {
    int s = i * 256 + tid;
    int line = s >> 3, u = s & 7, w = u ^ (line & 7);
    int row = (line << 1) | (w >> 2), ch = w & 3;
    sB[i] = w2t + ((size_t)e * DM + n0 + row) * DF + ch * 8;
    dB[i] = (unsigned)(8192 + i * 4096 + wv * 1024);
  }

  unsigned a_off[8], b_off[4];
  #pragma unroll
  for (int i = 0; i < 8; ++i) a_off[i] = swz_off(i * 16 + (lane & 15), lane >> 4);
  #pragma unroll
  for (int j = 0; j < 4; ++j) b_off[j] = 8192u + swz_off(wv * 64 + j * 16 + (lane & 15), lane >> 4);

  f32x4 acc[8][4];
  #pragma unroll
  for (int i = 0; i < 8; ++i)
    #pragma unroll
    for (int j = 0; j < 4; ++j)
      acc[i][j] = (f32x4){0.f, 0.f, 0.f, 0.f};

  KLOOP(DF / 32);

  int rq = (lane >> 4) << 2;
  int cbase = n0 + wv * 64 + (lane & 15);
  #pragma unroll
  for (int i = 0; i < 8; ++i) {
    #pragma unroll
    for (int q = 0; q < 4; ++q) {
      int mg = m0 + i * 16 + rq + q;
      if (mg < cnt) {
        size_t yrow = (size_t)(offe + mg) * DM;
        #pragma unroll
        for (int j = 0; j < 4; ++j) {
          int col = cbase + j * 16;
          Y[yrow + col] = (bf16_t)(acc[i][j][q] + b2[e * DM + col]);
        }
      }
    }
  }
}

// ===== combine: out[t] += g0*Y[s0] + g1*Y[s1] (one wave per token, bf16 Y) =====
__global__ __launch_bounds__(256) void k_combine(
    const bf16_t* __restrict__ Y, const int* __restrict__ t2s,
    const float* __restrict__ gl, float* __restrict__ out)
{
  int lane = threadIdx.x & 63, wv = threadIdx.x >> 6;
  int t = blockIdx.x * 4 + wv;
  int s0 = t2s[t*2], s1 = t2s[t*2 + 1];
  float g0 = gl[s0], g1 = gl[s1];
  const bf16_t* y0 = Y + (size_t)s0 * DM;
  const bf16_t* y1 = Y + (size_t)s1 * DM;
  float* o = out + (size_t)t * DM;
  #pragma unroll
  for (int c = 0; c < 4; ++c) {
    int d = c * 256 + lane * 4;
    float4 r  = *(const float4*)(o + d);
    bf16x4 a = *(const bf16x4*)(y0 + d);
    bf16x4 b = *(const bf16x4*)(y1 + d);
    r.x += g0 * (float)a[0] + g1 * (float)b[0];
    r.y += g0 * (float)a[1] + g1 * (float)b[1];
    r.z += g0 * (float)a[2] + g1 * (float)b[2];
    r.w += g0 * (float)a[3] + g1 * (float)b[3];
    *(float4*)(o + d) = r;
  }
}

// ============================ launch ============================
extern "C" void kernel_launch(void* const* d_in, const int* in_sizes, int n_in,
                              void* d_out, int out_size, void* d_ws, size_t ws_size,
                              hipStream_t stream) {
  const float* x      = (const float*)d_in[0];
  const float* gate_w = (const float*)d_in[1];
  const float* ln_g   = (const float*)d_in[2];
  const float* ln_b   = (const float*)d_in[3];
  const float* w1     = (const float*)d_in[4];
  const float* b1     = (const float*)d_in[5];
  const float* w2     = (const float*)d_in[6];
  const float* b2     = (const float*)d_in[7];
  float* out = (float*)d_out;

  char* ws = (char*)d_ws;
  bf16_t* xn   = (bf16_t*)(ws);                                  // 16 MiB
  bf16_t* w1t  = (bf16_t*)(ws + 16777216ull);                    // 64 MiB [E][F][D]; dead after ffn1
  bf16_t* Y    = (bf16_t*)(ws + 16777216ull);                    //   reused: Y [NP][DM] bf16 (32 MiB)
  bf16_t* w2t  = (bf16_t*)(ws + 83886080ull);                    // 64 MiB [E][D][F]
  bf16_t* H    = (bf16_t*)(ws + 150994944ull);                   // 128 MiB [NP][F]
  int*    list = (int*)   (ws + 285212672ull);
  float*  gl   = (float*) (ws + 285278208ull);
  int*    eidx = (int*)   (ws + 285343744ull);
  float*  gts  = (float*) (ws + 285409280ull);                   // aliased as t2s after k_assign
  int*    t2s  = (int*)   (ws + 285409280ull);
  int*    meta = (int*)   (ws + 285474816ull);

  hipMemsetAsync(meta, 0, 256, stream);
  k_router<<<T_TOK / 4, 256, 0, stream>>>(x, gate_w, ln_g, ln_b, out, xn, eidx, gts, meta);
  k_convT2<<<16384, 256, 0, stream>>>(w1, w1t, w2, w2t);
  k_finalize<<<1, 1, 0, stream>>>(meta, out + (size_t)T_TOK * DM);
  k_assign<<<T_TOK / 256, 256, 0, stream>>>(eidx, gts, meta, list, gl, t2s);
  k_ffn1<<<dim3(DF / 256, 64, NE), 256, 0, stream>>>(xn, w1t, b1, H, list, meta);
  k_ffn2<<<dim3(DM / 256, 64, NE), 256, 0, stream>>>(H, w2t, b2, Y, meta);
  k_combine<<<T_TOK / 4, 256, 0, stream>>>(Y, t2s, gl, out);
}

// Round 9
// 663.128 us; speedup vs baseline: 1.3727x; 1.0338x over previous
//
#include <hip/hip_runtime.h>
#include <math.h>

typedef __bf16 bf16_t;
typedef bf16_t bf16x8 __attribute__((ext_vector_type(8)));
typedef bf16_t bf16x4 __attribute__((ext_vector_type(4)));
typedef float  f32x4  __attribute__((ext_vector_type(4)));

#define T_TOK 8192
#define DM 1024
#define DF 4096
#define NE 8
#define NP 16384  // total token-expert pairs = T_TOK * 2

__device__ __forceinline__ f32x4 mfma_bf16(bf16x8 a, bf16x8 b, f32x4 c) {
  return __builtin_amdgcn_mfma_f32_16x16x32_bf16(a, b, c, 0, 0, 0);
}

__device__ __forceinline__ void gload16(const void* g, void* l) {
  __builtin_amdgcn_global_load_lds((const __attribute__((address_space(1))) void*)g,
                                   (__attribute__((address_space(3))) void*)l, 16, 0, 0);
}

// Abramowitz-Stegun 7.1.26 erf, |err| <= 1.5e-7
__device__ __forceinline__ float erf_fast(float x) {
  float ax = fabsf(x);
  float t = 1.f / (1.f + 0.3275911f * ax);
  float p = t * (0.254829592f + t * (-0.284496736f + t * (1.421413741f +
            t * (-1.453152027f + t * 1.061405429f))));
  float r = 1.f - p * __expf(-ax * ax);
  return copysignf(r, x);
}

// Line-pair LDS swizzle within a [256 rows][32 k] bf16 subtile (64B rows).
// byte(row,ch) = (row>>1)*128 + ((((row&1)<<2)|ch) ^ ((row>>1)&7))*16  [R7: 0 conflicts]
// Stage inverse for linear slot s: line=s>>3, u=s&7, w=u^(line&7), row=2*line+(w>>2), ch=w&3.
__device__ __forceinline__ unsigned swz_off(int row, int ch) {
  return (unsigned)(((row >> 1) << 7) + (((((row & 1) << 2) | ch) ^ ((row >> 1) & 7)) << 4));
}

// meta layout (ints): [0..7]=cnt1 [8..15]=cnt2 [16..23]=cursor [24..31]=off
// [32..39]=probsum(float) [40]=zsum(float)

// ============================ router ============================
__global__ __launch_bounds__(256) void k_router(
    const float* __restrict__ x, const float* __restrict__ gate_w,
    const float* __restrict__ ln_g, const float* __restrict__ ln_b,
    float* __restrict__ out, bf16_t* __restrict__ xn,
    int* __restrict__ eidx, float* __restrict__ gts, int* __restrict__ meta)
{
  int* cnt1 = meta;
  int* cnt2 = meta + 8;
  float* probsum = (float*)(meta + 32);
  float* zsum    = (float*)(meta + 40);

  __shared__ float sprob[8];
  __shared__ float sz;
  __shared__ int sc1[8], sc2[8];
  if (threadIdx.x < 8) { sprob[threadIdx.x] = 0.f; sc1[threadIdx.x] = 0; sc2[threadIdx.x] = 0; }
  if (threadIdx.x == 8) sz = 0.f;
  __syncthreads();

  int lane = threadIdx.x & 63, wv = threadIdx.x >> 6;
  int t = blockIdx.x * 4 + wv;
  const float* xt = x + (size_t)t * DM;

  float4 v[4];
  float s1 = 0.f, s2 = 0.f;
  #pragma unroll
  for (int c = 0; c < 4; ++c) {
    v[c] = *(const float4*)(xt + c * 256 + lane * 4);
    s1 += v[c].x + v[c].y + v[c].z + v[c].w;
    s2 += v[c].x * v[c].x + v[c].y * v[c].y + v[c].z * v[c].z + v[c].w * v[c].w;
  }
  #pragma unroll
  for (int o = 32; o > 0; o >>= 1) { s1 += __shfl_xor(s1, o, 64); s2 += __shfl_xor(s2, o, 64); }
  float mu = s1 * (1.f / DM);
  float var = s2 * (1.f / DM) - mu * mu;
  float rstd = rsqrtf(var + 1e-5f);

  float xv[16];
  #pragma unroll
  for (int c = 0; c < 4; ++c) {
    int d = c * 256 + lane * 4;
    float4 g4 = *(const float4*)(ln_g + d);
    float4 b4 = *(const float4*)(ln_b + d);
    xv[c*4+0] = (v[c].x - mu) * rstd * g4.x + b4.x;
    xv[c*4+1] = (v[c].y - mu) * rstd * g4.y + b4.y;
    xv[c*4+2] = (v[c].z - mu) * rstd * g4.z + b4.z;
    xv[c*4+3] = (v[c].w - mu) * rstd * g4.w + b4.w;
    *(float4*)(out + (size_t)t * DM + d) = v[c];  // residual init
    bf16x4 pk = { (bf16_t)xv[c*4+0], (bf16_t)xv[c*4+1], (bf16_t)xv[c*4+2], (bf16_t)xv[c*4+3] };
    *(bf16x4*)(xn + (size_t)t * DM + d) = pk;
  }

  float lg[8];
  #pragma unroll
  for (int e = 0; e < 8; ++e) {
    float p = 0.f;
    #pragma unroll
    for (int c = 0; c < 4; ++c) {
      int d = c * 256 + lane * 4;
      float4 g4 = *(const float4*)(gate_w + e * DM + d);
      p += xv[c*4+0] * g4.x + xv[c*4+1] * g4.y + xv[c*4+2] * g4.z + xv[c*4+3] * g4.w;
    }
    #pragma unroll
    for (int o = 32; o > 0; o >>= 1) p += __shfl_xor(p, o, 64);
    lg[e] = p;
  }

  if (lane == 0) {
    float m = -1e30f;
    #pragma unroll
    for (int e = 0; e < 8; ++e) { lg[e] = fminf(fmaxf(lg[e], -10.f), 10.f); m = fmaxf(m, lg[e]); }
    float pr[8]; float se = 0.f;
    #pragma unroll
    for (int e = 0; e < 8; ++e) { pr[e] = expf(lg[e] - m); se += pr[e]; }
    float inv = 1.f / se;
    #pragma unroll
    for (int e = 0; e < 8; ++e) pr[e] *= inv;
    float lse = m + logf(se);

    int e0 = 0; float p0 = pr[0];
    #pragma unroll
    for (int e = 1; e < 8; ++e) if (pr[e] > p0) { p0 = pr[e]; e0 = e; }
    int e1 = -1; float p1 = -1.f;
    #pragma unroll
    for (int e = 0; e < 8; ++e) if (e != e0 && pr[e] > p1) { p1 = pr[e]; e1 = e; }
    float s = p0 + p1 + 1e-8f;
    eidx[t*2]   = e0; eidx[t*2+1] = e1;
    gts[t*2]    = p0 / s; gts[t*2+1] = p1 / s;

    atomicAdd(&sc1[e0], 1);
    atomicAdd(&sc2[e0], 1);
    atomicAdd(&sc2[e1], 1);
    #pragma unroll
    for (int e = 0; e < 8; ++e) atomicAdd(&sprob[e], pr[e]);
    atomicAdd(&sz, lse * lse);
  }
  __syncthreads();
  if (threadIdx.x < 8) {
    if (sc1[threadIdx.x]) atomicAdd(&cnt1[threadIdx.x], sc1[threadIdx.x]);
    if (sc2[threadIdx.x]) atomicAdd(&cnt2[threadIdx.x], sc2[threadIdx.x]);
    atomicAdd(&probsum[threadIdx.x], sprob[threadIdx.x]);
  }
  if (threadIdx.x == 8) atomicAdd(zsum, sz);
}

// ========== merged weight convert+transpose (w1 and w2 in one grid) ==========
__global__ __launch_bounds__(256) void k_convT2(
    const float* __restrict__ w1, bf16_t* __restrict__ w1t,
    const float* __restrict__ w2, bf16_t* __restrict__ w2t)
{
  int bid = blockIdx.x;
  const float* s; bf16_t* d; int R, C, c0, r0;
  if (bid < 8192) {
    int e = bid >> 10, rem = bid & 1023;
    R = DM; C = DF;
    s = w1 + (size_t)e * R * C; d = w1t + (size_t)e * R * C;
    c0 = (rem & 63) * 64; r0 = (rem >> 6) * 64;
  } else {
    int e = (bid - 8192) >> 10, rem = (bid - 8192) & 1023;
    R = DF; C = DM;
    s = w2 + (size_t)e * R * C; d = w2t + (size_t)e * R * C;
    c0 = (rem & 15) * 64; r0 = (rem >> 4) * 64;
  }

  __shared__ float tile[64][65];
  int t = threadIdx.x;
  #pragma unroll
  for (int i = 0; i < 4; ++i) {
    int idx = i * 256 + t;
    int r = idx >> 4, c4 = (idx & 15) * 4;
    float4 v = *(const float4*)(s + (size_t)(r0 + r) * C + c0 + c4);
    tile[r][c4]   = v.x; tile[r][c4+1] = v.y;
    tile[r][c4+2] = v.z; tile[r][c4+3] = v.w;
  }
  __syncthreads();
  #pragma unroll
  for (int i = 0; i < 2; ++i) {
    int idx = i * 256 + t;
    int c = idx >> 3, r8 = (idx & 7) * 8;
    bf16x8 pk;
    #pragma unroll
    for (int k = 0; k < 8; ++k) pk[k] = (bf16_t)tile[r8 + k][c];
    *(bf16x8*)(d + (size_t)(c0 + c) * R + r0 + r8) = pk;
  }
}

// ============================ tiny serial kernels ============================
__global__ void k_finalize(int* __restrict__ meta, float* __restrict__ aux_out) {
  if (threadIdx.x == 0 && blockIdx.x == 0) {
    int acc = 0;
    for (int e = 0; e < 8; ++e) { meta[24 + e] = acc; acc += meta[8 + e]; }
    const float* probsum = (const float*)(meta + 32);
    const float* zsum    = (const float*)(meta + 40);
    float s = 0.f;
    for (int e = 0; e < 8; ++e)
      s += ((float)meta[e] * (1.f / 8192.f)) * (probsum[e] * (1.f / 8192.f));
    aux_out[0] = 8.f * s * 0.01f + (zsum[0] * (1.f / 8192.f)) * 0.001f;
  }
}

__global__ __launch_bounds__(256) void k_assign(
    const int* __restrict__ eidx, float* __restrict__ gts,
    int* __restrict__ meta, int* __restrict__ list, float* __restrict__ gl,
    int* __restrict__ t2s)
{
  int t = blockIdx.x * 256 + threadIdx.x;
  int* cursor = meta + 16;
  const int* off = meta + 24;
  #pragma unroll
  for (int k = 0; k < 2; ++k) {
    int e = eidx[t*2 + k];
    float g = gts[t*2 + k];          // read before aliased write
    int pos = atomicAdd(&cursor[e], 1);
    int slot = off[e] + pos;
    list[slot] = t;
    gl[slot] = g;
    t2s[t*2 + k] = slot;
  }
}

// ================= 8-phase 256x256 grouped GEMM (m201-style, hazard-ledgered) =================
// 8 waves (2M x 4N), per-wave out 128x64. LDS 128KB dynamic: buf P at P*65536;
// quarter-regions (16KB each): A_ks0 @0, A_ks1 @16384, B_ks0 @32768, B_ks1 @49152.
// Subtile [256 rows][32 k] line-pair swizzled (swz_off, R7-verified 0 conflicts);
// staged via pre-swizzled per-lane global source + linear gload_lds dest (rule #21).
//
// Phase (ks,nh) of tile T (buf P): ds_read frags + stage ONE quarter + [vmcnt] ->
// s_barrier -> setprio(1) 16 MFMA setprio(0) -> s_barrier.
// Quarter s (tile s>>2, region s&3; regions: 0=Akh0 1=Bkh0 2=Akh1 3=Bkh1) staged at
// global phase s-7 -> stage always lands one barrier AFTER the region's last reader:
//   Akh0 read q0 only (A-frags reg-reused in q1)  -> overwritten at q1
//   Bkh0 read q0,q1                               -> overwritten at q2
//   Akh1 read q2                                  -> overwritten at q3
//   Bkh1 read q2,q3                               -> overwritten at next tile's q0
// vmcnt(10) at q1/q3 (before mid-barrier) covers reads 6-7 phases ahead (2 loads/phase,
// FIFO: youngest-needed quarter has exactly 10 younger loads). vmcnt(0) once when
// staging ends; nothing after. Prologue stages quarters 0..6, vmcnt(10)+barrier.

#define PBAR do { __builtin_amdgcn_sched_barrier(0); __builtin_amdgcn_s_barrier(); \
                  __builtin_amdgcn_sched_barrier(0); } while (0)
#define VWAIT10 do { __builtin_amdgcn_sched_barrier(0); \
  asm volatile("s_waitcnt vmcnt(10)" ::: "memory"); \
  __builtin_amdgcn_sched_barrier(0); } while (0)
#define VWAIT0 do { __builtin_amdgcn_sched_barrier(0); \
  asm volatile("s_waitcnt vmcnt(0)" ::: "memory"); \
  __builtin_amdgcn_sched_barrier(0); } while (0)

#define STG_A(T, KS, P) do { \
  gload16(sAq[0] + (T)*64 + (KS)*32, smem + (P)*65536 + (KS)*16384 + dq[0]); \
  gload16(sAq[1] + (T)*64 + (KS)*32, smem + (P)*65536 + (KS)*16384 + dq[1]); } while (0)
#define STG_B(T, KS, P) do { \
  gload16(sBq[0] + (T)*64 + (KS)*32, smem + (P)*65536 + 32768 + (KS)*16384 + dq[0]); \
  gload16(sBq[1] + (T)*64 + (KS)*32, smem + (P)*65536 + 32768 + (KS)*16384 + dq[1]); } while (0)
#define LDA(P, KS) do { _Pragma("unroll") for (int i_ = 0; i_ < 8; ++i_) \
  afr[i_] = *(const bf16x8*)(smem + (P)*65536 + (KS)*16384 + a_off[i_]); } while (0)
#define LDB(P, KS, NH) do { \
  bfr0 = *(const bf16x8*)(smem + (P)*65536 + 32768 + (KS)*16384 + b_off[(NH)*2+0]); \
  bfr1 = *(const bf16x8*)(smem + (P)*65536 + 32768 + (KS)*16384 + b_off[(NH)*2+1]); } while (0)
#define FMA(NH) do { __builtin_amdgcn_s_setprio(1); \
  _Pragma("unroll") for (int i_ = 0; i_ < 8; ++i_) { \
    acc[i_][(NH)*2+0] = mfma_bf16(afr[i_], bfr0, acc[i_][(NH)*2+0]); \
    acc[i_][(NH)*2+1] = mfma_bf16(afr[i_], bfr1, acc[i_][(NH)*2+1]); } \
  __builtin_amdgcn_s_setprio(0); } while (0)

#define TILE_MAIN(T, P) do { \
  LDA(P,0); LDB(P,0,0); STG_B((T)+1, 1, (P)^1); PBAR; FMA(0); PBAR; \
  LDB(P,0,1); STG_A((T)+2, 0, P); VWAIT10; PBAR; FMA(1); PBAR; \
  LDA(P,1); LDB(P,1,0); STG_B((T)+2, 0, P); PBAR; FMA(0); PBAR; \
  LDB(P,1,1); STG_A((T)+2, 1, P); VWAIT10; PBAR; FMA(1); PBAR; } while (0)

#define GEMM_PIPE(NT) do { \
  STG_A(0,0,0); STG_B(0,0,0); STG_A(0,1,0); STG_B(0,1,0); \
  STG_A(1,0,1); STG_B(1,0,1); STG_A(1,1,1); \
  VWAIT10; PBAR; \
  for (int t_ = 0; t_ < (NT) - 2; t_ += 2) { TILE_MAIN(t_, 0); TILE_MAIN(t_ + 1, 1); } \
  /* tail tile NT-2 (P=0): stages last quarter, then drains */ \
  LDA(0,0); LDB(0,0,0); STG_B((NT)-1, 1, 1); PBAR; FMA(0); PBAR; \
  LDB(0,0,1); VWAIT0; PBAR; FMA(1); PBAR; \
  LDA(0,1); LDB(0,1,0); PBAR; FMA(0); PBAR; \
  LDB(0,1,1); PBAR; FMA(1); PBAR; \
  /* tail tile NT-1 (P=1): no stage, all data resident */ \
  LDA(1,0); LDB(1,0,0); PBAR; FMA(0); PBAR; \
  LDB(1,0,1); PBAR; FMA(1); PBAR; \
  LDA(1,1); LDB(1,1,0); PBAR; FMA(0); PBAR; \
  LDB(1,1,1); PBAR; FMA(1); \
} while (0)

// ============ GEMM1: H = gelu(Xn[list] @ W1t^T + b1), K=DM (NT=16) ============
__global__ __launch_bounds__(512, 1) void k_ffn1(
    const bf16_t* __restrict__ xn, const bf16_t* __restrict__ w1t,
    const float* __restrict__ b1, bf16_t* __restrict__ H,
    const int* __restrict__ list, const int* __restrict__ meta)
{
  extern __shared__ char smem[];
  int e = blockIdx.z;
  int cnt = meta[8 + e];
  int m0 = blockIdx.y * 256;
  if (m0 >= cnt) return;
  int offe = meta[24 + e];
  int n0 = blockIdx.x * 256;

  int tid = threadIdx.x, lane = tid & 63, wv = tid >> 6;
  int wm = wv >> 2, wn = wv & 3;

  const bf16_t* sAq[2]; const bf16_t* sBq[2];
  unsigned dq[2];
  #pragma unroll
  for (int i = 0; i < 2; ++i) {
    int s = i * 512 + tid;
    int line = s >> 3, u = s & 7, w = u ^ (line & 7);
    int row = (line << 1) | (w >> 2), ch = w & 3;
    int mrow = min(m0 + row, cnt - 1);
    int token = list[offe + mrow];
    sAq[i] = xn + (size_t)token * DM + ch * 8;
    sBq[i] = w1t + ((size_t)e * DF + n0 + row) * DM + ch * 8;
    dq[i] = (unsigned)(i * 8192 + wv * 1024);
  }

  unsigned a_off[8], b_off[4];
  #pragma unroll
  for (int i = 0; i < 8; ++i) a_off[i] = swz_off(wm * 128 + i * 16 + (lane & 15), lane >> 4);
  #pragma unroll
  for (int j = 0; j < 4; ++j)
    b_off[j] = swz_off(wn * 64 + (j >> 1) * 32 + (j & 1) * 16 + (lane & 15), lane >> 4);

  f32x4 acc[8][4];
  #pragma unroll
  for (int i = 0; i < 8; ++i)
    #pragma unroll
    for (int j = 0; j < 4; ++j)
      acc[i][j] = (f32x4){0.f, 0.f, 0.f, 0.f};
  bf16x8 afr[8], bfr0, bfr1;

  GEMM_PIPE(DM / 64);

  int rq = (lane >> 4) << 2;
  int cb = n0 + wn * 64 + (lane & 15);
  #pragma unroll
  for (int i = 0; i < 8; ++i) {
    #pragma unroll
    for (int q = 0; q < 4; ++q) {
      int mg = m0 + wm * 128 + i * 16 + rq + q;
      if (mg < cnt) {
        size_t hrow = (size_t)(offe + mg) * DF;
        #pragma unroll
        for (int j = 0; j < 4; ++j) {
          int col = cb + (j >> 1) * 32 + (j & 1) * 16;
          float hv = acc[i][j][q] + b1[e * DF + col];
          hv = 0.5f * hv * (1.f + erf_fast(hv * 0.70710678118f));
          H[hrow + col] = (bf16_t)hv;
        }
      }
    }
  }
}

// ============ GEMM2: Y[slot] = H[slot] @ W2t^T + b2 (bf16, no atomics), K=DF (NT=64) ============
__global__ __launch_bounds__(512, 1) void k_ffn2(
    const bf16_t* __restrict__ H, const bf16_t* __restrict__ w2t,
    const float* __restrict__ b2, bf16_t* __restrict__ Y,
    const int* __restrict__ meta)
{
  extern __shared__ char smem[];
  int e = blockIdx.z;
  int cnt = meta[8 + e];
  int m0 = blockIdx.y * 256;
  if (m0 >= cnt) return;
  int offe = meta[24 + e];
  int n0 = blockIdx.x * 256;

  int tid = threadIdx.x, lane = tid & 63, wv = tid >> 6;
  int wm = wv >> 2, wn = wv & 3;

  const bf16_t* sAq[2]; const bf16_t* sBq[2];
  unsigned dq[2];
  #pragma unroll
  for (int i = 0; i < 2; ++i) {
    int s = i * 512 + tid;
    int line = s >> 3, u = s & 7, w = u ^ (line & 7);
    int row = (line << 1) | (w >> 2), ch = w & 3;
    int mrow = min(m0 + row, cnt - 1);
    sAq[i] = H + (size_t)(offe + mrow) * DF + ch * 8;
    sBq[i] = w2t + ((size_t)e * DM + n0 + row) * DF + ch * 8;
    dq[i] = (unsigned)(i * 8192 + wv * 1024);
  }

  unsigned a_off[8], b_off[4];
  #pragma unroll
  for (int i = 0; i < 8; ++i) a_off[i] = swz_off(wm * 128 + i * 16 + (lane & 15), lane >> 4);
  #pragma unroll
  for (int j = 0; j < 4; ++j)
    b_off[j] = swz_off(wn * 64 + (j >> 1) * 32 + (j & 1) * 16 + (lane & 15), lane >> 4);

  f32x4 acc[8][4];
  #pragma unroll
  for (int i = 0; i < 8; ++i)
    #pragma unroll
    for (int j = 0; j < 4; ++j)
      acc[i][j] = (f32x4){0.f, 0.f, 0.f, 0.f};
  bf16x8 afr[8], bfr0, bfr1;

  GEMM_PIPE(DF / 64);

  int rq = (lane >> 4) << 2;
  int cb = n0 + wn * 64 + (lane & 15);
  #pragma unroll
  for (int i = 0; i < 8; ++i) {
    #pragma unroll
    for (int q = 0; q < 4; ++q) {
      int mg = m0 + wm * 128 + i * 16 + rq + q;
      if (mg < cnt) {
        size_t yrow = (size_t)(offe + mg) * DM;
        #pragma unroll
        for (int j = 0; j < 4; ++j) {
          int col = cb + (j >> 1) * 32 + (j & 1) * 16;
          Y[yrow + col] = (bf16_t)(acc[i][j][q] + b2[e * DM + col]);
        }
      }
    }
  }
}

// ===== combine: out[t] += g0*Y[s0] + g1*Y[s1] (one wave per token, bf16 Y) =====
__global__ __launch_bounds__(256) void k_combine(
    const bf16_t* __restrict__ Y, const int* __restrict__ t2s,
    const float* __restrict__ gl, float* __restrict__ out)
{
  int lane = threadIdx.x & 63, wv = threadIdx.x >> 6;
  int t = blockIdx.x * 4 + wv;
  int s0 = t2s[t*2], s1 = t2s[t*2 + 1];
  float g0 = gl[s0], g1 = gl[s1];
  const bf16_t* y0 = Y + (size_t)s0 * DM;
  const bf16_t* y1 = Y + (size_t)s1 * DM;
  float* o = out + (size_t)t * DM;
  #pragma unroll
  for (int c = 0; c < 4; ++c) {
    int d = c * 256 + lane * 4;
    float4 r  = *(const float4*)(o + d);
    bf16x4 a = *(const bf16x4*)(y0 + d);
    bf16x4 b = *(const bf16x4*)(y1 + d);
    r.x += g0 * (float)a[0] + g1 * (float)b[0];
    r.y += g0 * (float)a[1] + g1 * (float)b[1];
    r.z += g0 * (float)a[2] + g1 * (float)b[2];
    r.w += g0 * (float)a[3] + g1 * (float)b[3];
    *(float4*)(o + d) = r;
  }
}

// ============================ launch ============================
extern "C" void kernel_launch(void* const* d_in, const int* in_sizes, int n_in,
                              void* d_out, int out_size, void* d_ws, size_t ws_size,
                              hipStream_t stream) {
  const float* x      = (const float*)d_in[0];
  const float* gate_w = (const float*)d_in[1];
  const float* ln_g   = (const float*)d_in[2];
  const float* ln_b   = (const float*)d_in[3];
  const float* w1     = (const float*)d_in[4];
  const float* b1     = (const float*)d_in[5];
  const float* w2     = (const float*)d_in[6];
  const float* b2     = (const float*)d_in[7];
  float* out = (float*)d_out;

  char* ws = (char*)d_ws;
  bf16_t* xn   = (bf16_t*)(ws);                                  // 16 MiB
  bf16_t* w1t  = (bf16_t*)(ws + 16777216ull);                    // 64 MiB [E][F][D]; dead after ffn1
  bf16_t* Y    = (bf16_t*)(ws + 16777216ull);                    //   reused: Y [NP][DM] bf16 (32 MiB)
  bf16_t* w2t  = (bf16_t*)(ws + 83886080ull);                    // 64 MiB [E][D][F]
  bf16_t* H    = (bf16_t*)(ws + 150994944ull);                   // 128 MiB [NP][F]
  int*    list = (int*)   (ws + 285212672ull);
  float*  gl   = (float*) (ws + 285278208ull);
  int*    eidx = (int*)   (ws + 285343744ull);
  float*  gts  = (float*) (ws + 285409280ull);                   // aliased as t2s after k_assign
  int*    t2s  = (int*)   (ws + 285409280ull);
  int*    meta = (int*)   (ws + 285474816ull);

  hipFuncSetAttribute((const void*)k_ffn1, hipFuncAttributeMaxDynamicSharedMemorySize, 131072);
  hipFuncSetAttribute((const void*)k_ffn2, hipFuncAttributeMaxDynamicSharedMemorySize, 131072);

  hipMemsetAsync(meta, 0, 256, stream);
  k_router<<<T_TOK / 4, 256, 0, stream>>>(x, gate_w, ln_g, ln_b, out, xn, eidx, gts, meta);
  k_convT2<<<16384, 256, 0, stream>>>(w1, w1t, w2, w2t);
  k_finalize<<<1, 1, 0, stream>>>(meta, out + (size_t)T_TOK * DM);
  k_assign<<<T_TOK / 256, 256, 0, stream>>>(eidx, gts, meta, list, gl, t2s);
  k_ffn1<<<dim3(DF / 256, 32, NE), 512, 131072, stream>>>(xn, w1t, b1, H, list, meta);
  k_ffn2<<<dim3(DM / 256, 32, NE), 512, 131072, stream>>>(H, w2t, b2, Y, meta);
  k_combine<<<T_TOK / 4, 256, 0, stream>>>(Y, t2s, gl, out);
}

// Round 10
// 648.656 us; speedup vs baseline: 1.4033x; 1.0223x over previous
//
#include <hip/hip_runtime.h>
#include <math.h>

typedef __bf16 bf16_t;
typedef bf16_t bf16x8 __attribute__((ext_vector_type(8)));
typedef bf16_t bf16x4 __attribute__((ext_vector_type(4)));
typedef float  f32x4  __attribute__((ext_vector_type(4)));

#define T_TOK 8192
#define DM 1024
#define DF 4096
#define NE 8
#define NP 16384  // total token-expert pairs = T_TOK * 2

__device__ __forceinline__ f32x4 mfma_bf16(bf16x8 a, bf16x8 b, f32x4 c) {
  return __builtin_amdgcn_mfma_f32_16x16x32_bf16(a, b, c, 0, 0, 0);
}

__device__ __forceinline__ void gload16(const void* g, void* l) {
  __builtin_amdgcn_global_load_lds((const __attribute__((address_space(1))) void*)g,
                                   (__attribute__((address_space(3))) void*)l, 16, 0, 0);
}

// Abramowitz-Stegun 7.1.26 erf, |err| <= 1.5e-7
__device__ __forceinline__ float erf_fast(float x) {
  float ax = fabsf(x);
  float t = 1.f / (1.f + 0.3275911f * ax);
  float p = t * (0.254829592f + t * (-0.284496736f + t * (1.421413741f +
            t * (-1.453152027f + t * 1.061405429f))));
  float r = 1.f - p * __expf(-ax * ax);
  return copysignf(r, x);
}

// Line-pair LDS swizzle within a [256 rows][32 k] bf16 subtile (64B rows).
// byte(row,ch) = (row>>1)*128 + ((((row&1)<<2)|ch) ^ ((row>>1)&7))*16  [R7: 0 conflicts]
__device__ __forceinline__ unsigned swz_off(int row, int ch) {
  return (unsigned)(((row >> 1) << 7) + (((((row & 1) << 2) | ch) ^ ((row >> 1) & 7)) << 4));
}

// meta layout (ints): [0..7]=cnt1 [8..15]=cnt2 [16..23]=cursor [24..31]=off
// [32..39]=probsum(float) [40]=zsum(float)

// ============================ router ============================
__global__ __launch_bounds__(256) void k_router(
    const float* __restrict__ x, const float* __restrict__ gate_w,
    const float* __restrict__ ln_g, const float* __restrict__ ln_b,
    float* __restrict__ out, bf16_t* __restrict__ xn,
    int* __restrict__ eidx, float* __restrict__ gts, int* __restrict__ meta)
{
  int* cnt1 = meta;
  int* cnt2 = meta + 8;
  float* probsum = (float*)(meta + 32);
  float* zsum    = (float*)(meta + 40);

  __shared__ float sprob[8];
  __shared__ float sz;
  __shared__ int sc1[8], sc2[8];
  if (threadIdx.x < 8) { sprob[threadIdx.x] = 0.f; sc1[threadIdx.x] = 0; sc2[threadIdx.x] = 0; }
  if (threadIdx.x == 8) sz = 0.f;
  __syncthreads();

  int lane = threadIdx.x & 63, wv = threadIdx.x >> 6;
  int t = blockIdx.x * 4 + wv;
  const float* xt = x + (size_t)t * DM;

  float4 v[4];
  float s1 = 0.f, s2 = 0.f;
  #pragma unroll
  for (int c = 0; c < 4; ++c) {
    v[c] = *(const float4*)(xt + c * 256 + lane * 4);
    s1 += v[c].x + v[c].y + v[c].z + v[c].w;
    s2 += v[c].x * v[c].x + v[c].y * v[c].y + v[c].z * v[c].z + v[c].w * v[c].w;
  }
  #pragma unroll
  for (int o = 32; o > 0; o >>= 1) { s1 += __shfl_xor(s1, o, 64); s2 += __shfl_xor(s2, o, 64); }
  float mu = s1 * (1.f / DM);
  float var = s2 * (1.f / DM) - mu * mu;
  float rstd = rsqrtf(var + 1e-5f);

  float xv[16];
  #pragma unroll
  for (int c = 0; c < 4; ++c) {
    int d = c * 256 + lane * 4;
    float4 g4 = *(const float4*)(ln_g + d);
    float4 b4 = *(const float4*)(ln_b + d);
    xv[c*4+0] = (v[c].x - mu) * rstd * g4.x + b4.x;
    xv[c*4+1] = (v[c].y - mu) * rstd * g4.y + b4.y;
    xv[c*4+2] = (v[c].z - mu) * rstd * g4.z + b4.z;
    xv[c*4+3] = (v[c].w - mu) * rstd * g4.w + b4.w;
    *(float4*)(out + (size_t)t * DM + d) = v[c];  // residual init
    bf16x4 pk = { (bf16_t)xv[c*4+0], (bf16_t)xv[c*4+1], (bf16_t)xv[c*4+2], (bf16_t)xv[c*4+3] };
    *(bf16x4*)(xn + (size_t)t * DM + d) = pk;
  }

  float lg[8];
  #pragma unroll
  for (int e = 0; e < 8; ++e) {
    float p = 0.f;
    #pragma unroll
    for (int c = 0; c < 4; ++c) {
      int d = c * 256 + lane * 4;
      float4 g4 = *(const float4*)(gate_w + e * DM + d);
      p += xv[c*4+0] * g4.x + xv[c*4+1] * g4.y + xv[c*4+2] * g4.z + xv[c*4+3] * g4.w;
    }
    #pragma unroll
    for (int o = 32; o > 0; o >>= 1) p += __shfl_xor(p, o, 64);
    lg[e] = p;
  }

  if (lane == 0) {
    float m = -1e30f;
    #pragma unroll
    for (int e = 0; e < 8; ++e) { lg[e] = fminf(fmaxf(lg[e], -10.f), 10.f); m = fmaxf(m, lg[e]); }
    float pr[8]; float se = 0.f;
    #pragma unroll
    for (int e = 0; e < 8; ++e) { pr[e] = expf(lg[e] - m); se += pr[e]; }
    float inv = 1.f / se;
    #pragma unroll
    for (int e = 0; e < 8; ++e) pr[e] *= inv;
    float lse = m + logf(se);

    int e0 = 0; float p0 = pr[0];
    #pragma unroll
    for (int e = 1; e < 8; ++e) if (pr[e] > p0) { p0 = pr[e]; e0 = e; }
    int e1 = -1; float p1 = -1.f;
    #pragma unroll
    for (int e = 0; e < 8; ++e) if (e != e0 && pr[e] > p1) { p1 = pr[e]; e1 = e; }
    float s = p0 + p1 + 1e-8f;
    eidx[t*2]   = e0; eidx[t*2+1] = e1;
    gts[t*2]    = p0 / s; gts[t*2+1] = p1 / s;

    atomicAdd(&sc1[e0], 1);
    atomicAdd(&sc2[e0], 1);
    atomicAdd(&sc2[e1], 1);
    #pragma unroll
    for (int e = 0; e < 8; ++e) atomicAdd(&sprob[e], pr[e]);
    atomicAdd(&sz, lse * lse);
  }
  __syncthreads();
  if (threadIdx.x < 8) {
    if (sc1[threadIdx.x]) atomicAdd(&cnt1[threadIdx.x], sc1[threadIdx.x]);
    if (sc2[threadIdx.x]) atomicAdd(&cnt2[threadIdx.x], sc2[threadIdx.x]);
    atomicAdd(&probsum[threadIdx.x], sprob[threadIdx.x]);
  }
  if (threadIdx.x == 8) atomicAdd(zsum, sz);
}

// ========== merged weight convert+transpose (w1 and w2 in one grid) ==========
__global__ __launch_bounds__(256) void k_convT2(
    const float* __restrict__ w1, bf16_t* __restrict__ w1t,
    const float* __restrict__ w2, bf16_t* __restrict__ w2t)
{
  int bid = blockIdx.x;
  const float* s; bf16_t* d; int R, C, c0, r0;
  if (bid < 8192) {
    int e = bid >> 10, rem = bid & 1023;
    R = DM; C = DF;
    s = w1 + (size_t)e * R * C; d = w1t + (size_t)e * R * C;
    c0 = (rem & 63) * 64; r0 = (rem >> 6) * 64;
  } else {
    int e = (bid - 8192) >> 10, rem = (bid - 8192) & 1023;
    R = DF; C = DM;
    s = w2 + (size_t)e * R * C; d = w2t + (size_t)e * R * C;
    c0 = (rem & 15) * 64; r0 = (rem >> 4) * 64;
  }

  __shared__ float tile[64][65];
  int t = threadIdx.x;
  #pragma unroll
  for (int i = 0; i < 4; ++i) {
    int idx = i * 256 + t;
    int r = idx >> 4, c4 = (idx & 15) * 4;
    float4 v = *(const float4*)(s + (size_t)(r0 + r) * C + c0 + c4);
    tile[r][c4]   = v.x; tile[r][c4+1] = v.y;
    tile[r][c4+2] = v.z; tile[r][c4+3] = v.w;
  }
  __syncthreads();
  #pragma unroll
  for (int i = 0; i < 2; ++i) {
    int idx = i * 256 + t;
    int c = idx >> 3, r8 = (idx & 7) * 8;
    bf16x8 pk;
    #pragma unroll
    for (int k = 0; k < 8; ++k) pk[k] = (bf16_t)tile[r8 + k][c];
    *(bf16x8*)(d + (size_t)(c0 + c) * R + r0 + r8) = pk;
  }
}

// ============================ tiny serial kernels ============================
__global__ void k_finalize(int* __restrict__ meta, float* __restrict__ aux_out) {
  if (threadIdx.x == 0 && blockIdx.x == 0) {
    int acc = 0;
    for (int e = 0; e < 8; ++e) { meta[24 + e] = acc; acc += meta[8 + e]; }
    const float* probsum = (const float*)(meta + 32);
    const float* zsum    = (const float*)(meta + 40);
    float s = 0.f;
    for (int e = 0; e < 8; ++e)
      s += ((float)meta[e] * (1.f / 8192.f)) * (probsum[e] * (1.f / 8192.f));
    aux_out[0] = 8.f * s * 0.01f + (zsum[0] * (1.f / 8192.f)) * 0.001f;
  }
}

__global__ __launch_bounds__(256) void k_assign(
    const int* __restrict__ eidx, float* __restrict__ gts,
    int* __restrict__ meta, int* __restrict__ list, float* __restrict__ gl,
    int* __restrict__ t2s)
{
  int t = blockIdx.x * 256 + threadIdx.x;
  int* cursor = meta + 16;
  const int* off = meta + 24;
  #pragma unroll
  for (int k = 0; k < 2; ++k) {
    int e = eidx[t*2 + k];
    float g = gts[t*2 + k];          // read before aliased write
    int pos = atomicAdd(&cursor[e], 1);
    int slot = off[e] + pos;
    list[slot] = t;
    gl[slot] = g;
    t2s[t*2 + k] = slot;
  }
}

// ====== 256x256 grouped GEMM, 4-phase/K-tile, 1 barrier/phase, reg-dbuf ======
// 8 waves (2Mx4N), per-wave 128x64. LDS 128KB dynamic: buf P @P*65536;
// regions (16KB): A_ks0 @0, A_ks1 @16384, B_ks0 @32768, B_ks1 @49152.
// Line-pair swizzle (0 conflicts, R7). Pre-swizzled global src + linear gload dest.
//
// Phase (ks,nh) of tile t (buf P): stage one quarter of t+1 into P^1; counted vmcnt
// (FIFO-derived: 6 at nh0, 8 at nh1); s_barrier; sched_barrier(0) [pin reads below
// barrier]; ds_reads + 16 MFMA in ONE free region (compiler interleaves with counted
// lgkmcnt). Register dbuf kills cross-phase VGPR WAR: afr0/afr1 by ks, bfrA/bfrB pairs
// alternate by phase; acc quadrant rotates nh0/nh1 so MFMA pipe drains past barriers.
// LDS WAR slack: every region overwritten >=4 barriers after its last read. Tail tile
// peeled with vmcnt {4,4,0,0}.

#define VW(N) asm volatile("s_waitcnt vmcnt(" #N ")" ::: "memory")
#define BARSB do { __builtin_amdgcn_s_barrier(); __builtin_amdgcn_sched_barrier(0); } while (0)

#define STG_A(T, KS, P) do { \
  gload16(sAq[0] + (T)*64 + (KS)*32, smem + (P)*65536 + (KS)*16384 + dq[0]); \
  gload16(sAq[1] + (T)*64 + (KS)*32, smem + (P)*65536 + (KS)*16384 + dq[1]); } while (0)
#define STG_B(T, KS, P) do { \
  gload16(sBq[0] + (T)*64 + (KS)*32, smem + (P)*65536 + 32768 + (KS)*16384 + dq[0]); \
  gload16(sBq[1] + (T)*64 + (KS)*32, smem + (P)*65536 + 32768 + (KS)*16384 + dq[1]); } while (0)

#define LDA_(AF, P, KS) do { _Pragma("unroll") for (int i_ = 0; i_ < 8; ++i_) \
  AF[i_] = *(const bf16x8*)(smem + (P)*65536 + (KS)*16384 + a_off[i_]); } while (0)
#define LDBA(P, KS) do { \
  bfrA0 = *(const bf16x8*)(smem + (P)*65536 + 32768 + (KS)*16384 + b_off[0]); \
  bfrA1 = *(const bf16x8*)(smem + (P)*65536 + 32768 + (KS)*16384 + b_off[1]); } while (0)
#define LDBB(P, KS) do { \
  bfrB0 = *(const bf16x8*)(smem + (P)*65536 + 32768 + (KS)*16384 + b_off[2]); \
  bfrB1 = *(const bf16x8*)(smem + (P)*65536 + 32768 + (KS)*16384 + b_off[3]); } while (0)

#define FMAQ(AF, B0, B1, NH) do { __builtin_amdgcn_s_setprio(1); \
  _Pragma("unroll") for (int i_ = 0; i_ < 8; ++i_) { \
    acc[i_][(NH)*2+0] = mfma_bf16(AF[i_], B0, acc[i_][(NH)*2+0]); \
    acc[i_][(NH)*2+1] = mfma_bf16(AF[i_], B1, acc[i_][(NH)*2+1]); } \
  __builtin_amdgcn_s_setprio(0); } while (0)

#define TILE(T, P) do { \
  STG_A((T)+1, 0, (P)^1); VW(6); BARSB; \
  LDA_(afr0, P, 0); LDBA(P, 0); FMAQ(afr0, bfrA0, bfrA1, 0); \
  STG_B((T)+1, 0, (P)^1); VW(8); BARSB; \
  LDBB(P, 0); FMAQ(afr0, bfrB0, bfrB1, 1); \
  STG_A((T)+1, 1, (P)^1); VW(6); BARSB; \
  LDA_(afr1, P, 1); LDBA(P, 1); FMAQ(afr1, bfrA0, bfrA1, 0); \
  STG_B((T)+1, 1, (P)^1); VW(8); BARSB; \
  LDBB(P, 1); FMAQ(afr1, bfrB0, bfrB1, 1); \
} while (0)

#define TAIL(P) do { \
  VW(4); BARSB; LDA_(afr0, P, 0); LDBA(P, 0); FMAQ(afr0, bfrA0, bfrA1, 0); \
  VW(4); BARSB; LDBB(P, 0); FMAQ(afr0, bfrB0, bfrB1, 1); \
  VW(0); BARSB; LDA_(afr1, P, 1); LDBA(P, 1); FMAQ(afr1, bfrA0, bfrA1, 0); \
  VW(0); BARSB; LDBB(P, 1); FMAQ(afr1, bfrB0, bfrB1, 1); \
} while (0)

#define GEMM_PIPE(NT) do { \
  STG_A(0, 0, 0); STG_B(0, 0, 0); STG_A(0, 1, 0); STG_B(0, 1, 0); \
  for (int t_ = 0; t_ + 2 < (NT); t_ += 2) { TILE(t_, 0); TILE(t_ + 1, 1); } \
  TILE((NT) - 2, 0); \
  TAIL(1); \
} while (0)

// ============ GEMM1: H = gelu(Xn[list] @ W1t^T + b1), K=DM (NT=16) ============
__global__ __launch_bounds__(512, 1) void k_ffn1(
    const bf16_t* __restrict__ xn, const bf16_t* __restrict__ w1t,
    const float* __restrict__ b1, bf16_t* __restrict__ H,
    const int* __restrict__ list, const int* __restrict__ meta)
{
  extern __shared__ char smem[];
  int e = blockIdx.z;
  int cnt = meta[8 + e];
  int m0 = blockIdx.y * 256;
  if (m0 >= cnt) return;
  int offe = meta[24 + e];
  int n0 = blockIdx.x * 256;

  int tid = threadIdx.x, lane = tid & 63, wv = tid >> 6;
  int wm = wv >> 2, wn = wv & 3;

  const bf16_t* sAq[2]; const bf16_t* sBq[2];
  unsigned dq[2];
  #pragma unroll
  for (int i = 0; i < 2; ++i) {
    int s = i * 512 + tid;
    int line = s >> 3, u = s & 7, w = u ^ (line & 7);
    int row = (line << 1) | (w >> 2), ch = w & 3;
    int mrow = min(m0 + row, cnt - 1);
    int token = list[offe + mrow];
    sAq[i] = xn + (size_t)token * DM + ch * 8;
    sBq[i] = w1t + ((size_t)e * DF + n0 + row) * DM + ch * 8;
    dq[i] = (unsigned)(i * 8192 + wv * 1024);
  }

  unsigned a_off[8], b_off[4];
  #pragma unroll
  for (int i = 0; i < 8; ++i) a_off[i] = swz_off(wm * 128 + i * 16 + (lane & 15), lane >> 4);
  #pragma unroll
  for (int j = 0; j < 4; ++j)
    b_off[j] = swz_off(wn * 64 + (j >> 1) * 32 + (j & 1) * 16 + (lane & 15), lane >> 4);

  f32x4 acc[8][4];
  #pragma unroll
  for (int i = 0; i < 8; ++i)
    #pragma unroll
    for (int j = 0; j < 4; ++j)
      acc[i][j] = (f32x4){0.f, 0.f, 0.f, 0.f};
  bf16x8 afr0[8], afr1[8], bfrA0, bfrA1, bfrB0, bfrB1;

  GEMM_PIPE(DM / 64);

  int rq = (lane >> 4) << 2;
  int cb = n0 + wn * 64 + (lane & 15);
  #pragma unroll
  for (int i = 0; i < 8; ++i) {
    #pragma unroll
    for (int q = 0; q < 4; ++q) {
      int mg = m0 + wm * 128 + i * 16 + rq + q;
      if (mg < cnt) {
        size_t hrow = (size_t)(offe + mg) * DF;
        #pragma unroll
        for (int j = 0; j < 4; ++j) {
          int col = cb + (j >> 1) * 32 + (j & 1) * 16;
          float hv = acc[i][j][q] + b1[e * DF + col];
          hv = 0.5f * hv * (1.f + erf_fast(hv * 0.70710678118f));
          H[hrow + col] = (bf16_t)hv;
        }
      }
    }
  }
}

// ============ GEMM2: Y[slot] = H[slot] @ W2t^T + b2 (bf16, no atomics), K=DF (NT=64) ============
__global__ __launch_bounds__(512, 1) void k_ffn2(
    const bf16_t* __restrict__ H, const bf16_t* __restrict__ w2t,
    const float* __restrict__ b2, bf16_t* __restrict__ Y,
    const int* __restrict__ meta)
{
  extern __shared__ char smem[];
  int e = blockIdx.z;
  int cnt = meta[8 + e];
  int m0 = blockIdx.y * 256;
  if (m0 >= cnt) return;
  int offe = meta[24 + e];
  int n0 = blockIdx.x * 256;

  int tid = threadIdx.x, lane = tid & 63, wv = tid >> 6;
  int wm = wv >> 2, wn = wv & 3;

  const bf16_t* sAq[2]; const bf16_t* sBq[2];
  unsigned dq[2];
  #pragma unroll
  for (int i = 0; i < 2; ++i) {
    int s = i * 512 + tid;
    int line = s >> 3, u = s & 7, w = u ^ (line & 7);
    int row = (line << 1) | (w >> 2), ch = w & 3;
    int mrow = min(m0 + row, cnt - 1);
    sAq[i] = H + (size_t)(offe + mrow) * DF + ch * 8;
    sBq[i] = w2t + ((size_t)e * DM + n0 + row) * DF + ch * 8;
    dq[i] = (unsigned)(i * 8192 + wv * 1024);
  }

  unsigned a_off[8], b_off[4];
  #pragma unroll
  for (int i = 0; i < 8; ++i) a_off[i] = swz_off(wm * 128 + i * 16 + (lane & 15), lane >> 4);
  #pragma unroll
  for (int j = 0; j < 4; ++j)
    b_off[j] = swz_off(wn * 64 + (j >> 1) * 32 + (j & 1) * 16 + (lane & 15), lane >> 4);

  f32x4 acc[8][4];
  #pragma unroll
  for (int i = 0; i < 8; ++i)
    #pragma unroll
    for (int j = 0; j < 4; ++j)
      acc[i][j] = (f32x4){0.f, 0.f, 0.f, 0.f};
  bf16x8 afr0[8], afr1[8], bfrA0, bfrA1, bfrB0, bfrB1;

  GEMM_PIPE(DF / 64);

  int rq = (lane >> 4) << 2;
  int cb = n0 + wn * 64 + (lane & 15);
  #pragma unroll
  for (int i = 0; i < 8; ++i) {
    #pragma unroll
    for (int q = 0; q < 4; ++q) {
      int mg = m0 + wm * 128 + i * 16 + rq + q;
      if (mg < cnt) {
        size_t yrow = (size_t)(offe + mg) * DM;
        #pragma unroll
        for (int j = 0; j < 4; ++j) {
          int col = cb + (j >> 1) * 32 + (j & 1) * 16;
          Y[yrow + col] = (bf16_t)(acc[i][j][q] + b2[e * DM + col]);
        }
      }
    }
  }
}

// ===== combine: out[t] += g0*Y[s0] + g1*Y[s1] (one wave per token, bf16 Y) =====
__global__ __launch_bounds__(256) void k_combine(
    const bf16_t* __restrict__ Y, const int* __restrict__ t2s,
    const float* __restrict__ gl, float* __restrict__ out)
{
  int lane = threadIdx.x & 63, wv = threadIdx.x >> 6;
  int t = blockIdx.x * 4 + wv;
  int s0 = t2s[t*2], s1 = t2s[t*2 + 1];
  float g0 = gl[s0], g1 = gl[s1];
  const bf16_t* y0 = Y + (size_t)s0 * DM;
  const bf16_t* y1 = Y + (size_t)s1 * DM;
  float* o = out + (size_t)t * DM;
  #pragma unroll
  for (int c = 0; c < 4; ++c) {
    int d = c * 256 + lane * 4;
    float4 r  = *(const float4*)(o + d);
    bf16x4 a = *(const bf16x4*)(y0 + d);
    bf16x4 b = *(const bf16x4*)(y1 + d);
    r.x += g0 * (float)a[0] + g1 * (float)b[0];
    r.y += g0 * (float)a[1] + g1 * (float)b[1];
    r.z += g0 * (float)a[2] + g1 * (float)b[2];
    r.w += g0 * (float)a[3] + g1 * (float)b[3];
    *(float4*)(o + d) = r;
  }
}

// ============================ launch ============================
extern "C" void kernel_launch(void* const* d_in, const int* in_sizes, int n_in,
                              void* d_out, int out_size, void* d_ws, size_t ws_size,
                              hipStream_t stream) {
  const float* x      = (const float*)d_in[0];
  const float* gate_w = (const float*)d_in[1];
  const float* ln_g   = (const float*)d_in[2];
  const float* ln_b   = (const float*)d_in[3];
  const float* w1     = (const float*)d_in[4];
  const float* b1     = (const float*)d_in[5];
  const float* w2     = (const float*)d_in[6];
  const float* b2     = (const float*)d_in[7];
  float* out = (float*)d_out;

  char* ws = (char*)d_ws;
  bf16_t* xn   = (bf16_t*)(ws);                                  // 16 MiB
  bf16_t* w1t  = (bf16_t*)(ws + 16777216ull);                    // 64 MiB [E][F][D]; dead after ffn1
  bf16_t* Y    = (bf16_t*)(ws + 16777216ull);                    //   reused: Y [NP][DM] bf16 (32 MiB)
  bf16_t* w2t  = (bf16_t*)(ws + 83886080ull);                    // 64 MiB [E][D][F]
  bf16_t* H    = (bf16_t*)(ws + 150994944ull);                   // 128 MiB [NP][F]
  int*    list = (int*)   (ws + 285212672ull);
  float*  gl   = (float*) (ws + 285278208ull);
  int*    eidx = (int*)   (ws + 285343744ull);
  float*  gts  = (float*) (ws + 285409280ull);                   // aliased as t2s after k_assign
  int*    t2s  = (int*)   (ws + 285409280ull);
  int*    meta = (int*)   (ws + 285474816ull);

  hipFuncSetAttribute((const void*)k_ffn1, hipFuncAttributeMaxDynamicSharedMemorySize, 131072);
  hipFuncSetAttribute((const void*)k_ffn2, hipFuncAttributeMaxDynamicSharedMemorySize, 131072);

  hipMemsetAsync(meta, 0, 256, stream);
  k_router<<<T_TOK / 4, 256, 0, stream>>>(x, gate_w, ln_g, ln_b, out, xn, eidx, gts, meta);
  k_convT2<<<16384, 256, 0, stream>>>(w1, w1t, w2, w2t);
  k_finalize<<<1, 1, 0, stream>>>(meta, out + (size_t)T_TOK * DM);
  k_assign<<<T_TOK / 256, 256, 0, stream>>>(eidx, gts, meta, list, gl, t2s);
  k_ffn1<<<dim3(DF / 256, 32, NE), 512, 131072, stream>>>(xn, w1t, b1, H, list, meta);
  k_ffn2<<<dim3(DM / 256, 32, NE), 512, 131072, stream>>>(H, w2t, b2, Y, meta);
  k_combine<<<T_TOK / 4, 256, 0, stream>>>(Y, t2s, gl, out);
}